// Round 10
// baseline (1518.512 us; speedup 1.0000x reference)
//
#include <hip/hip_runtime.h>
#include <stdint.h>

#define NT   8192
#define DI   2048
#define DH   16384
#define DO   2048
#define KSEL 64
#define EPS_SEL 0.004f
#define BCAP 256
#define KSTEPS 64   // K=2048 / BK=32 for the 128^2 skip GEMM

typedef _Float16 f16;
typedef f16  f16x8 __attribute__((ext_vector_type(8)));
typedef float f32x4 __attribute__((ext_vector_type(4)));
typedef unsigned short usx8 __attribute__((ext_vector_type(8)));

__device__ __forceinline__ unsigned short f2h_bits(float x){
  f16 h = (f16)x;
  union { f16 h; unsigned short u; } c; c.h = h; return c.u;
}
__device__ __forceinline__ float h_bits2f(unsigned short u){
  union { unsigned short u; f16 h; } c; c.u = u; return (float)c.h;
}

__device__ __forceinline__ void gload16(const void* g, void* lds){
  __builtin_amdgcn_global_load_lds(
    (const __attribute__((address_space(1))) void*)(uintptr_t)g,
    (__attribute__((address_space(3))) void*)(uint32_t)(uintptr_t)lds,
    16, 0, 0);
}

// ---------------- f32 -> f16 convert (vector8) ----------------
__global__ __launch_bounds__(256) void k_cvt(const float* __restrict__ in,
                                             unsigned short* __restrict__ out, int n8)
{
  int i = blockIdx.x*256 + threadIdx.x;
  if (i >= n8) return;
  const float4* p = (const float4*)in + (size_t)i*2;
  float4 a = p[0], b = p[1];
  union { f16 h[8]; usx8 u; } r;
  r.h[0]=(f16)a.x; r.h[1]=(f16)a.y; r.h[2]=(f16)a.z; r.h[3]=(f16)a.w;
  r.h[4]=(f16)b.x; r.h[5]=(f16)b.y; r.h[6]=(f16)b.z; r.h[7]=(f16)b.w;
  ((usx8*)out)[i] = r.u;
}

// ---------------- W_dec [DO][DH] f32 -> WdecT [DH][DO] f16 ----------------
__global__ __launch_bounds__(256) void k_transpose_cvt(const float* __restrict__ W,
                                                       unsigned short* __restrict__ WT)
{
  __shared__ unsigned short t[64][65];
  const int r0 = blockIdx.x*64;   // over DO
  const int c0 = blockIdx.y*64;   // over DH
  const int tid = threadIdx.x;
  const int q = tid >> 6, s = tid & 63;
#pragma unroll
  for (int i=0;i<16;i++){
    int r = q + i*4;
    t[r][s] = f2h_bits(W[(size_t)(r0+r)*DH + c0 + s]);
  }
  __syncthreads();
#pragma unroll
  for (int i=0;i<16;i++){
    int c = q + i*4;
    WT[(size_t)(c0+c)*DO + r0 + s] = t[s][c];
  }
}

// ================= 256^2 8-phase encoder GEMM (m201 template) =================
// R8-proven: full 3-bit chunk swizzle (chunk ^= row&7, involution both sides);
// bank conflicts measured 0.
__global__ __launch_bounds__(512, 2) void k_gemm_enc8(
    const unsigned short* __restrict__ Ap,
    const unsigned short* __restrict__ Bp,
    const float* __restrict__ bias,
    unsigned short* __restrict__ C)
{
  __shared__ unsigned short lds[65536];   // 128 KB
  const int tid  = threadIdx.x;
  const int lane = tid & 63;
  const int wv   = tid >> 6;
  const int wm   = wv >> 2;     // 0..1
  const int wn   = wv & 3;      // 0..3
  const int bm   = blockIdx.x;  // fastest -> B-panel reuse (R5-proven)
  const int bn   = blockIdx.y;
  const int fr   = lane & 15;
  const int fq   = lane >> 4;

  f32x4 acc[8][4];
#pragma unroll
  for (int i=0;i<8;i++)
#pragma unroll
    for (int j=0;j<4;j++) acc[i][j] = (f32x4){0.f,0.f,0.f,0.f};

  f16x8 ar[4][2];
  f16x8 br[2][2];

#define STAGE_HALF(t, ab, h) do { \
    const unsigned short* G_ = (ab) ? Bp : Ap; \
    const int rb_ = ((ab) ? bn : bm)*256 + (h)*128; \
    const int k0_ = (t)*64; \
    const int db_ = ((t)&1)*32768 + (ab)*16384 + (h)*8192; \
    _Pragma("unroll") \
    for (int is_=0; is_<2; ++is_){ \
      const int cw_ = wv*64 + is_*512; \
      const int cl_ = cw_ + lane; \
      const int cs_ = cl_ ^ ((cl_>>3)&7); \
      gload16(G_ + (size_t)(rb_ + (cs_>>3))*DI + k0_ + (cs_&7)*8, \
              (unsigned short*)lds + db_ + cw_*8); \
    } } while(0)

#define LD_A(buf, mh) do { \
    const int ba_ = (buf)*32768 + (mh)*8192; \
    _Pragma("unroll") \
    for (int mf_=0; mf_<4; ++mf_) \
    _Pragma("unroll") \
    for (int ks_=0; ks_<2; ++ks_){ \
      const int lin_ = (wm*64 + mf_*16 + fr)*128 + (ks_*4 + fq)*16; \
      const int sz_  = lin_ ^ ((((lin_>>7)&7))<<4); \
      ar[mf_][ks_] = *(const f16x8*)&lds[ba_ + (sz_>>1)]; \
    } } while(0)

#define LD_B(buf, nh) do { \
    const int bb_ = (buf)*32768 + 16384 + (nh)*8192; \
    _Pragma("unroll") \
    for (int nf_=0; nf_<2; ++nf_) \
    _Pragma("unroll") \
    for (int ks_=0; ks_<2; ++ks_){ \
      const int lin_ = (wn*32 + nf_*16 + fr)*128 + (ks_*4 + fq)*16; \
      const int sz_  = lin_ ^ ((((lin_>>7)&7))<<4); \
      br[nf_][ks_] = *(const f16x8*)&lds[bb_ + (sz_>>1)]; \
    } } while(0)

#define MM(mh, nh) do { \
    _Pragma("unroll") \
    for (int mf_=0; mf_<4; ++mf_) \
    _Pragma("unroll") \
    for (int nf_=0; nf_<2; ++nf_) \
    _Pragma("unroll") \
    for (int ks_=0; ks_<2; ++ks_) \
      acc[(mh)*4+mf_][(nh)*2+nf_] = __builtin_amdgcn_mfma_f32_16x16x32_f16( \
          ar[mf_][ks_], br[nf_][ks_], acc[(mh)*4+mf_][(nh)*2+nf_], 0, 0, 0); \
  } while(0)

#define VM6 asm volatile("s_waitcnt vmcnt(6)" ::: "memory")
#define VM0 asm volatile("s_waitcnt vmcnt(0)" ::: "memory")

#define PH(buf, mh, nh, LA_, LB_, STG, VM) do { \
    if (LA_) LD_A(buf, mh); \
    if (LB_) LD_B(buf, nh); \
    STG; \
    VM; \
    __builtin_amdgcn_s_barrier(); \
    asm volatile("s_waitcnt lgkmcnt(0)" ::: "memory"); \
    __builtin_amdgcn_sched_barrier(0); \
    __builtin_amdgcn_s_setprio(1); \
    MM(mh, nh); \
    __builtin_amdgcn_s_setprio(0); \
    __builtin_amdgcn_s_barrier(); \
  } while(0)

  STAGE_HALF(0,0,0); STAGE_HALF(0,1,1); STAGE_HALF(0,0,1); STAGE_HALF(0,1,0);
  STAGE_HALF(1,0,0); STAGE_HALF(1,1,1); STAGE_HALF(1,0,1);
  asm volatile("s_waitcnt vmcnt(6)" ::: "memory");
  __builtin_amdgcn_s_barrier();

  for (int j = 0; j < 15; ++j) {
    const int a = 2*j, b = 2*j+1;
    PH(0, 0,0, 1,1, STAGE_HALF(b,  1,0), (void)0);
    PH(0, 0,1, 0,1, STAGE_HALF(a+2,0,0), (void)0);
    PH(0, 1,1, 1,0, STAGE_HALF(a+2,1,1), (void)0);
    PH(0, 1,0, 0,1, STAGE_HALF(a+2,0,1), VM6);
    PH(1, 0,0, 1,1, STAGE_HALF(a+2,1,0), (void)0);
    PH(1, 0,1, 0,1, STAGE_HALF(b+2,0,0), (void)0);
    PH(1, 1,1, 1,0, STAGE_HALF(b+2,1,1), (void)0);
    PH(1, 1,0, 0,1, STAGE_HALF(b+2,0,1), VM6);
  }
  PH(0, 0,0, 1,1, STAGE_HALF(31,1,0), (void)0);
  PH(0, 0,1, 0,1, (void)0, (void)0);
  PH(0, 1,1, 1,0, (void)0, (void)0);
  PH(0, 1,0, 0,1, (void)0, VM0);
  PH(1, 0,0, 1,1, (void)0, (void)0);
  PH(1, 0,1, 0,1, (void)0, (void)0);
  PH(1, 1,1, 1,0, (void)0, (void)0);
  PH(1, 1,0, 0,1, (void)0, (void)0);

#undef PH
#undef VM6
#undef VM0
#undef MM
#undef LD_B
#undef LD_A
#undef STAGE_HALF

#pragma unroll
  for (int nh=0; nh<2; ++nh)
#pragma unroll
  for (int nf=0; nf<2; ++nf){
    const int col = bn*256 + nh*128 + wn*32 + nf*16 + fr;
    const float bs = bias[col];
#pragma unroll
    for (int mh=0; mh<2; ++mh)
#pragma unroll
    for (int mf=0; mf<4; ++mf){
      const int row0 = bm*256 + mh*128 + wm*64 + mf*16 + fq*4;
#pragma unroll
      for (int q=0; q<4; ++q)
        C[(size_t)(row0+q)*DH + col] = f2h_bits(acc[mh*4+mf][nh*2+nf][q] + bs);
    }
  }
}

// ---------------- 128^2 2-phase GEMM body (skip GEMM) ----------------
template<bool F16OUT>
__device__ __forceinline__ void gemm_body(
    const unsigned short* __restrict__ A,
    const unsigned short* __restrict__ B,
    const float* __restrict__ bias1,
    const float* __restrict__ bias2,
    void* __restrict__ Cout,
    int N, int Kd)
{
  __shared__ unsigned short lA[2][128*32];
  __shared__ unsigned short lB[2][128*32];
  const int tid  = threadIdx.x;
  const int lane = tid & 63;
  const int wv   = tid >> 6;
  const int bm   = blockIdx.x, bn = blockIdx.y;
  const int wm   = wv >> 1, wn = wv & 1;

  f32x4 acc[4][4];
#pragma unroll
  for (int m=0;m<4;m++)
#pragma unroll
    for (int n=0;n<4;n++) acc[m][n] = (f32x4){0.f,0.f,0.f,0.f};

  const int lr  = lane >> 2;
  const int kq4 = lane & 3;
  const unsigned short* gA = A + (size_t)(bm*128 + wv*16 + lr)*Kd + kq4*8;
  const unsigned short* gB = B + (size_t)(bn*128 + wv*16 + lr)*Kd + kq4*8;

#define STAGE(BUF, KS) do { \
    const int _ko = (KS)*32; \
    gload16(gA + _ko,                  &lA[BUF][wv*512]); \
    gload16(gA + _ko + (size_t)64*Kd,  &lA[BUF][2048 + wv*512]); \
    gload16(gB + _ko,                  &lB[BUF][wv*512]); \
    gload16(gB + _ko + (size_t)64*Kd,  &lB[BUF][2048 + wv*512]); \
  } while(0)

#define COMPUTE(BUF) do { \
    const int kq = (lane >> 4) * 8; \
    const int rr = lane & 15; \
    f16x8 af[4], bf[4]; \
    _Pragma("unroll") \
    for (int m=0;m<4;m++) \
      af[m] = *(const f16x8*)&lA[BUF][(wm*64 + m*16 + rr)*32 + kq]; \
    _Pragma("unroll") \
    for (int n=0;n<4;n++) \
      bf[n] = *(const f16x8*)&lB[BUF][(wn*64 + n*16 + rr)*32 + kq]; \
    _Pragma("unroll") \
    for (int m=0;m<4;m++) \
      _Pragma("unroll") \
      for (int n=0;n<4;n++) \
        acc[m][n] = __builtin_amdgcn_mfma_f32_16x16x32_f16(af[m], bf[n], acc[m][n], 0, 0, 0); \
  } while(0)

  STAGE(0, 0);
  __syncthreads();
  for (int e = 0; e < KSTEPS-2; e += 2) {
    STAGE(1, e+1); COMPUTE(0); __syncthreads();
    STAGE(0, e+2); COMPUTE(1); __syncthreads();
  }
  STAGE(1, KSTEPS-1); COMPUTE(0); __syncthreads();
  COMPUTE(1);

#undef STAGE
#undef COMPUTE

  const int rowBase = bm*128 + wm*64 + ((lane>>4)<<2);
  const int colBase = bn*128 + wn*64 + (lane & 15);
#pragma unroll
  for (int n=0;n<4;n++) {
    const int col = colBase + n*16;
    float bs = bias1[col];
    if (bias2) bs += bias2[col];
#pragma unroll
    for (int m=0;m<4;m++) {
#pragma unroll
      for (int q=0;q<4;q++) {
        const int row = rowBase + m*16 + q;
        float v = acc[m][n][q] + bs;
        if (F16OUT) ((unsigned short*)Cout)[(size_t)row*N + col] = f2h_bits(v);
        else        ((float*)Cout)[(size_t)row*N + col] = v;
      }
    }
  }
}

__global__ __launch_bounds__(256) void k_gemm_skip(
    const unsigned short* __restrict__ A, const unsigned short* __restrict__ B,
    const float* __restrict__ bias1, const float* __restrict__ bias2,
    void* __restrict__ Cout)
{
  gemm_body<false>(A, B, bias1, bias2, Cout, DO, DI);
}

// ---------------- exact top-64 per row (wave-parallel) ----------------
// R9 change: pass-1 histogram copies keyed by lane&7 (8 copies) instead of
// per-wave. A wave's 64 lanes spread over 8 copies -> intra-wave same-address
// atomic serialization drops 64 -> <=8 deep; copies sit in distinct banks
// ((c*256+bucket)%32 differs per c) so spread copies proceed in parallel.
__global__ __launch_bounds__(256) void k_topk(
    const unsigned short* __restrict__ P,
    const float* __restrict__ X,
    const float* __restrict__ Wenc,
    const float* __restrict__ benc,
    int*   __restrict__ candIdx,
    float* __restrict__ candVal)
{
  __shared__ unsigned int hist8[8][256];
  __shared__ unsigned int hist2[256];
  __shared__ int   inIdx[64];
  __shared__ float inVal[64];
  __shared__ int    bandIdx[BCAP];
  __shared__ double bandVal[BCAP];
  __shared__ int s_inCnt, s_bandCnt, s_sel, s_above, s_sel2;

  const int r = blockIdx.x;
  const int tid = threadIdx.x;
  const int wv = tid >> 6, lane = tid & 63;
  const int lc = lane & 7;            // histogram copy for this lane
  const unsigned short* Prow = P + (size_t)r*DH;

#pragma unroll
  for (int k=0;k<8;k++) hist8[k][tid & 255] = 0;
  hist2[tid] = 0;
  if (tid==0){ s_inCnt=0; s_bandCnt=0; }
  __syncthreads();

  usx8 ch[8];
#pragma unroll
  for (int k=0;k<8;k++) ch[k] = ((const usx8*)Prow)[tid + k*256];
#pragma unroll
  for (int k=0;k<8;k++)
#pragma unroll
    for (int e=0;e<8;e++){
      unsigned short b = ch[k][e];
      unsigned short o = (b & 0x8000) ? (unsigned short)~b : (unsigned short)(b|0x8000);
      atomicAdd(&hist8[lc][o>>8], 1u);
    }
  __syncthreads();
  {
    unsigned int hs = 0;
#pragma unroll
    for (int c=0;c<8;c++) hs += hist8[c][tid];
    hist8[0][tid] = hs;
  }
  __syncthreads();

  if (tid < 64) {
    const int h0 = 255 - 4*tid;
    unsigned int c0=hist8[0][h0], c1=hist8[0][h0-1], c2=hist8[0][h0-2], c3=hist8[0][h0-3];
    unsigned int s = c0+c1+c2+c3;
    unsigned int Pi = s;
#pragma unroll
    for (int off=1; off<64; off<<=1){
      unsigned int t = __shfl_up(Pi, off);
      if (tid >= off) Pi += t;
    }
    unsigned long long mk = __ballot(Pi >= KSEL);
    int cr = (int)__builtin_ctzll(mk);
    if (tid == cr){
      unsigned int cum = Pi - s;
      unsigned int cc[4] = {c0,c1,c2,c3};
#pragma unroll
      for (int j=0;j<4;j++){
        if (cum + cc[j] >= KSEL){ s_sel = h0-j; s_above = (int)cum; break; }
        cum += cc[j];
      }
    }
  }
  __syncthreads();
  const int bsel = s_sel; const int cntAbove = s_above;

#pragma unroll
  for (int k=0;k<8;k++)
#pragma unroll
    for (int e=0;e<8;e++){
      unsigned short b = ch[k][e];
      unsigned short o = (b & 0x8000) ? (unsigned short)~b : (unsigned short)(b|0x8000);
      if ((int)(o>>8) == bsel) atomicAdd(&hist2[o & 0xff], 1u);
    }
  __syncthreads();
  {
    const int K2 = KSEL - cntAbove;
    if (tid < 64) {
      const int h0 = 255 - 4*tid;
      unsigned int c0=hist2[h0], c1=hist2[h0-1], c2=hist2[h0-2], c3=hist2[h0-3];
      unsigned int s = c0+c1+c2+c3;
      unsigned int Pi = s;
#pragma unroll
      for (int off=1; off<64; off<<=1){
        unsigned int t = __shfl_up(Pi, off);
        if (tid >= off) Pi += t;
      }
      unsigned long long mk = __ballot(Pi >= (unsigned)K2);
      int cr = (int)__builtin_ctzll(mk);
      if (tid == cr){
        unsigned int cum = Pi - s;
        unsigned int cc[4] = {c0,c1,c2,c3};
#pragma unroll
        for (int j=0;j<4;j++){
          if (cum + cc[j] >= (unsigned)K2){ s_sel2 = h0-j; break; }
          cum += cc[j];
        }
      }
    }
  }
  __syncthreads();

  unsigned short To = (unsigned short)((bsel<<8) | s_sel2);
  unsigned short tb = (To & 0x8000) ? (unsigned short)(To ^ 0x8000) : (unsigned short)~To;
  const float T = h_bits2f(tb);
  const float hiv = T + 2.0f*EPS_SEL, lov = T - 2.0f*EPS_SEL;

#pragma unroll
  for (int k=0;k<8;k++)
#pragma unroll
    for (int e=0;e<8;e++){
      unsigned short b = ch[k][e];
      float v = h_bits2f(b);
      if (v > hiv){
        int p = atomicAdd(&s_inCnt,1);
        if (p < 64){ inIdx[p] = (tid + k*256)*8 + e; inVal[p] = v; }
      } else if (v >= lov){
        int p = atomicAdd(&s_bandCnt,1);
        if (p < BCAP) bandIdx[p] = (tid + k*256)*8 + e;
      }
    }
  __syncthreads();
  const int m = s_inCnt < 64 ? s_inCnt : 64;
  const int B = s_bandCnt < BCAP ? s_bandCnt : BCAP;

  const float* Xr = X + (size_t)r*DI;
  for (int b=wv; b<B; b+=4){
    const int j = bandIdx[b];
    const float* Wr = Wenc + (size_t)j*DI;
    double s = 0.0;
    for (int k=lane; k<DI; k+=64)
      s = fma((double)Xr[k], (double)Wr[k], s);
#pragma unroll
    for (int off=32; off>=1; off>>=1) s += __shfl_down(s, off);
    if (lane==0) bandVal[b] = s + (double)benc[j];
  }
  __syncthreads();

  int* ci = candIdx + (size_t)r*KSEL;
  float* cv = candVal + (size_t)r*KSEL;
  for (int t=tid; t<m; t+=256){ ci[t]=inIdx[t]; cv[t]=inVal[t]; }

  const int need = KSEL - m;
  if (tid < 64 && need > 0){
    unsigned int used = 0;
    for (int t=0;t<need;t++){
      double best = -1.0e300; int bi = -1;
#pragma unroll
      for (int sIt=0;sIt<4;sIt++){
        int b = tid + sIt*64;
        if (b < B && !((used>>sIt)&1)){
          double v = bandVal[b];
          if (v > best){ best=v; bi=b; }
        }
      }
#pragma unroll
      for (int off=32; off>=1; off>>=1){
        double ov = __shfl_down(best, off);
        int    oi = __shfl_down(bi,   off);
        if (ov > best){ best = ov; bi = oi; }
      }
      bi   = __shfl(bi, 0);
      best = __shfl(best, 0);
      if ((bi & 63) == tid) used |= 1u << (bi >> 6);
      if (tid == 0){
        ci[m+t] = bandIdx[bi];
        cv[m+t] = (float)best;
      }
    }
  }
}

// ---------------- sparse decode + loss partial ----------------
__global__ __launch_bounds__(256) void k_decode(
    float* __restrict__ outhat,
    const unsigned short* __restrict__ WdT,
    const int*   __restrict__ candIdx,
    const float* __restrict__ candVal,
    const float* __restrict__ target,
    float* __restrict__ lossPartial)
{
  __shared__ int   sIdx[KSEL];
  __shared__ float sVal[KSEL];
  __shared__ float wsum[4];
  const int r = blockIdx.x, tid = threadIdx.x;
  if (tid < KSEL){
    sIdx[tid]=candIdx[(size_t)r*KSEL+tid];
    float v=candVal[(size_t)r*KSEL+tid];
    sVal[tid] = v>0.f ? v : 0.f;
  }
  __syncthreads();
  float* orow = outhat + (size_t)r*DO;
  float a[8];
  {
    float4 v0 = *(const float4*)(orow + tid*8);
    float4 v1 = *(const float4*)(orow + tid*8 + 4);
    a[0]=v0.x;a[1]=v0.y;a[2]=v0.z;a[3]=v0.w;a[4]=v1.x;a[5]=v1.y;a[6]=v1.z;a[7]=v1.w;
  }
  for (int c=0;c<KSEL;c++){
    const float v = sVal[c];
    if (v==0.f) continue;
    const f16x8 w = *(const f16x8*)(WdT + (size_t)sIdx[c]*DO + tid*8);
#pragma unroll
    for (int j=0;j<8;j++) a[j] = fmaf(v, (float)w[j], a[j]);
  }
  const float* trow = target + (size_t)r*DO;
  float4 t0 = *(const float4*)(trow + tid*8);
  float4 t1 = *(const float4*)(trow + tid*8 + 4);
  float tt[8] = {t0.x,t0.y,t0.z,t0.w,t1.x,t1.y,t1.z,t1.w};
  float ls = 0.f;
#pragma unroll
  for (int j=0;j<8;j++){ float d = a[j]-tt[j]; ls = fmaf(d,d,ls); }
  {
    float4 v0 = {a[0],a[1],a[2],a[3]}, v1 = {a[4],a[5],a[6],a[7]};
    *(float4*)(orow + tid*8) = v0;
    *(float4*)(orow + tid*8 + 4) = v1;
  }
#pragma unroll
  for (int off=32; off>=1; off>>=1) ls += __shfl_down(ls, off);
  if ((tid&63)==0) wsum[tid>>6]=ls;
  __syncthreads();
  if (tid==0)
    lossPartial[r] = (wsum[0]+wsum[1]+wsum[2]+wsum[3]) * (1.0f/((float)NT*(float)DO));
}

__global__ __launch_bounds__(256) void k_lossreduce(const float* __restrict__ lp,
                                                    float* __restrict__ out)
{
  __shared__ double ws[4];
  double s=0.0;
  for (int i=threadIdx.x;i<NT;i+=256) s += (double)lp[i];
#pragma unroll
  for (int off=32; off>=1; off>>=1) s += __shfl_down(s, off);
  if ((threadIdx.x&63)==0) ws[threadIdx.x>>6]=s;
  __syncthreads();
  if (threadIdx.x==0) *out = (float)(ws[0]+ws[1]+ws[2]+ws[3]);
}

// ---------------- finalize h: zero + scatter ----------------
__global__ __launch_bounds__(256) void k_scatter(
    float* __restrict__ H, const int* __restrict__ candIdx, const float* __restrict__ candVal)
{
  const int r=blockIdx.x, tid=threadIdx.x;
  float* hr = H + (size_t)r*DH;
  const float4 z = {0.f,0.f,0.f,0.f};
#pragma unroll
  for (int i=0;i<16;i++) ((float4*)hr)[tid + i*256] = z;
  __syncthreads();
  if (tid<KSEL){
    float v = candVal[(size_t)r*KSEL+tid];
    hr[candIdx[(size_t)r*KSEL+tid]] = v>0.f ? v : 0.f;
  }
}

extern "C" void kernel_launch(void* const* d_in, const int* in_sizes, int n_in,
                              void* d_out, int out_size, void* d_ws, size_t ws_size,
                              hipStream_t stream)
{
  const float* X     = (const float*)d_in[0];
  const float* tgt   = (const float*)d_in[1];
  const float* Wenc  = (const float*)d_in[2];
  const float* benc  = (const float*)d_in[3];
  const float* Wdec  = (const float*)d_in[4];
  const float* bdec  = (const float*)d_in[5];
  const float* Wskip = (const float*)d_in[6];
  const float* bskip = (const float*)d_in[7];

  float* out     = (float*)d_out;
  float* outhat  = out;
  float* H       = out + (size_t)NT*DO;
  float* lossOut = out + (size_t)NT*DO + (size_t)NT*DH;

  // h-region scratch plan (dead until k_scatter)
  char* hb = (char*)H;
  unsigned short* P      = (unsigned short*)hb;
  char* U                = hb + (size_t)NT*DH*2;
  unsigned short* Xh     = (unsigned short*)U;
  unsigned short* Wench  = (unsigned short*)(U + (size_t)NT*DI*2);
  unsigned short* Wskiph = (unsigned short*)(U + (size_t)NT*DI*2 + (size_t)DH*DI*2);
  unsigned short* WdTh   = (unsigned short*)(U + (size_t)NT*DI*2 + (size_t)DH*DI*2 + (size_t)DO*DI*2);

  int*   candIdx    = (int*)d_ws;
  float* candVal    = (float*)((char*)d_ws + (size_t)NT*KSEL*4);
  float* lossPartial= (float*)((char*)d_ws + (size_t)NT*KSEL*8);

  k_cvt<<<NT*DI/8/256, 256, 0, stream>>>(X, Xh, NT*DI/8);
  k_cvt<<<DH*DI/8/256, 256, 0, stream>>>(Wenc, Wench, DH*DI/8);
  k_cvt<<<DO*DI/8/256, 256, 0, stream>>>(Wskip, Wskiph, DO*DI/8);
  k_transpose_cvt<<<dim3(DO/64, DH/64), 256, 0, stream>>>(Wdec, WdTh);

  k_gemm_enc8<<<dim3(NT/256, DH/256), 512, 0, stream>>>(Xh, Wench, benc, P);
  k_topk<<<NT, 256, 0, stream>>>(P, X, Wenc, benc, candIdx, candVal);
  k_gemm_skip<<<dim3(NT/128, DO/128), 256, 0, stream>>>(Xh, Wskiph, bdec, bskip, (void*)outhat);
  k_decode<<<NT, 256, 0, stream>>>(outhat, WdTh, candIdx, candVal, tgt, lossPartial);
  k_lossreduce<<<1, 256, 0, stream>>>(lossPartial, lossOut);
  k_scatter<<<NT, 256, 0, stream>>>(H, candIdx, candVal);
}

// Round 11
// 1472.230 us; speedup vs baseline: 1.0314x; 1.0314x over previous
//
#include <hip/hip_runtime.h>
#include <stdint.h>

#define NT   8192
#define DI   2048
#define DH   16384
#define DO   2048
#define KSEL 64
#define EPS_SEL 0.004f
#define BCAP 256
#define KSTEPS 64   // K=2048 / BK=32 for the 128^2 skip GEMM

typedef _Float16 f16;
typedef f16  f16x8 __attribute__((ext_vector_type(8)));
typedef float f32x4 __attribute__((ext_vector_type(4)));
typedef unsigned short usx8 __attribute__((ext_vector_type(8)));

__device__ __forceinline__ unsigned short f2h_bits(float x){
  f16 h = (f16)x;
  union { f16 h; unsigned short u; } c; c.h = h; return c.u;
}
__device__ __forceinline__ float h_bits2f(unsigned short u){
  union { unsigned short u; f16 h; } c; c.u = u; return (float)c.h;
}

__device__ __forceinline__ void gload16(const void* g, void* lds){
  __builtin_amdgcn_global_load_lds(
    (const __attribute__((address_space(1))) void*)(uintptr_t)g,
    (__attribute__((address_space(3))) void*)(uint32_t)(uintptr_t)lds,
    16, 0, 0);
}

// ---------------- f32 -> f16 convert (vector8) ----------------
__global__ __launch_bounds__(256) void k_cvt(const float* __restrict__ in,
                                             unsigned short* __restrict__ out, int n8)
{
  int i = blockIdx.x*256 + threadIdx.x;
  if (i >= n8) return;
  const float4* p = (const float4*)in + (size_t)i*2;
  float4 a = p[0], b = p[1];
  union { f16 h[8]; usx8 u; } r;
  r.h[0]=(f16)a.x; r.h[1]=(f16)a.y; r.h[2]=(f16)a.z; r.h[3]=(f16)a.w;
  r.h[4]=(f16)b.x; r.h[5]=(f16)b.y; r.h[6]=(f16)b.z; r.h[7]=(f16)b.w;
  ((usx8*)out)[i] = r.u;
}

// ---------------- W_dec [DO][DH] f32 -> WdecT [DH][DO] f16 ----------------
__global__ __launch_bounds__(256) void k_transpose_cvt(const float* __restrict__ W,
                                                       unsigned short* __restrict__ WT)
{
  __shared__ unsigned short t[64][65];
  const int r0 = blockIdx.x*64;   // over DO
  const int c0 = blockIdx.y*64;   // over DH
  const int tid = threadIdx.x;
  const int q = tid >> 6, s = tid & 63;
#pragma unroll
  for (int i=0;i<16;i++){
    int r = q + i*4;
    t[r][s] = f2h_bits(W[(size_t)(r0+r)*DH + c0 + s]);
  }
  __syncthreads();
#pragma unroll
  for (int i=0;i<16;i++){
    int c = q + i*4;
    WT[(size_t)(c0+c)*DO + r0 + s] = t[s][c];
  }
}

// ================= 256^2 8-phase encoder GEMM (m201 template) =================
// R8-proven: full 3-bit chunk swizzle (conflicts = 0). R10: coalesced epilogue —
// acc staged to LDS ([128][264] f16, 16B-aligned rows, two mh passes), read
// back linearly, stored as f16x8 in 64B segments (was: 64 scattered b16 stores).
__global__ __launch_bounds__(512, 2) void k_gemm_enc8(
    const unsigned short* __restrict__ Ap,
    const unsigned short* __restrict__ Bp,
    const float* __restrict__ bias,
    unsigned short* __restrict__ C)
{
  __shared__ unsigned short lds[65536];   // 128 KB
  const int tid  = threadIdx.x;
  const int lane = tid & 63;
  const int wv   = tid >> 6;
  const int wm   = wv >> 2;     // 0..1
  const int wn   = wv & 3;      // 0..3
  const int bm   = blockIdx.x;  // fastest -> B-panel reuse (R5-proven)
  const int bn   = blockIdx.y;
  const int fr   = lane & 15;
  const int fq   = lane >> 4;

  f32x4 acc[8][4];
#pragma unroll
  for (int i=0;i<8;i++)
#pragma unroll
    for (int j=0;j<4;j++) acc[i][j] = (f32x4){0.f,0.f,0.f,0.f};

  f16x8 ar[4][2];
  f16x8 br[2][2];

#define STAGE_HALF(t, ab, h) do { \
    const unsigned short* G_ = (ab) ? Bp : Ap; \
    const int rb_ = ((ab) ? bn : bm)*256 + (h)*128; \
    const int k0_ = (t)*64; \
    const int db_ = ((t)&1)*32768 + (ab)*16384 + (h)*8192; \
    _Pragma("unroll") \
    for (int is_=0; is_<2; ++is_){ \
      const int cw_ = wv*64 + is_*512; \
      const int cl_ = cw_ + lane; \
      const int cs_ = cl_ ^ ((cl_>>3)&7); \
      gload16(G_ + (size_t)(rb_ + (cs_>>3))*DI + k0_ + (cs_&7)*8, \
              (unsigned short*)lds + db_ + cw_*8); \
    } } while(0)

#define LD_A(buf, mh) do { \
    const int ba_ = (buf)*32768 + (mh)*8192; \
    _Pragma("unroll") \
    for (int mf_=0; mf_<4; ++mf_) \
    _Pragma("unroll") \
    for (int ks_=0; ks_<2; ++ks_){ \
      const int lin_ = (wm*64 + mf_*16 + fr)*128 + (ks_*4 + fq)*16; \
      const int sz_  = lin_ ^ ((((lin_>>7)&7))<<4); \
      ar[mf_][ks_] = *(const f16x8*)&lds[ba_ + (sz_>>1)]; \
    } } while(0)

#define LD_B(buf, nh) do { \
    const int bb_ = (buf)*32768 + 16384 + (nh)*8192; \
    _Pragma("unroll") \
    for (int nf_=0; nf_<2; ++nf_) \
    _Pragma("unroll") \
    for (int ks_=0; ks_<2; ++ks_){ \
      const int lin_ = (wn*32 + nf_*16 + fr)*128 + (ks_*4 + fq)*16; \
      const int sz_  = lin_ ^ ((((lin_>>7)&7))<<4); \
      br[nf_][ks_] = *(const f16x8*)&lds[bb_ + (sz_>>1)]; \
    } } while(0)

#define MM(mh, nh) do { \
    _Pragma("unroll") \
    for (int mf_=0; mf_<4; ++mf_) \
    _Pragma("unroll") \
    for (int nf_=0; nf_<2; ++nf_) \
    _Pragma("unroll") \
    for (int ks_=0; ks_<2; ++ks_) \
      acc[(mh)*4+mf_][(nh)*2+nf_] = __builtin_amdgcn_mfma_f32_16x16x32_f16( \
          ar[mf_][ks_], br[nf_][ks_], acc[(mh)*4+mf_][(nh)*2+nf_], 0, 0, 0); \
  } while(0)

#define VM6 asm volatile("s_waitcnt vmcnt(6)" ::: "memory")
#define VM0 asm volatile("s_waitcnt vmcnt(0)" ::: "memory")

#define PH(buf, mh, nh, LA_, LB_, STG, VM) do { \
    if (LA_) LD_A(buf, mh); \
    if (LB_) LD_B(buf, nh); \
    STG; \
    VM; \
    __builtin_amdgcn_s_barrier(); \
    asm volatile("s_waitcnt lgkmcnt(0)" ::: "memory"); \
    __builtin_amdgcn_sched_barrier(0); \
    __builtin_amdgcn_s_setprio(1); \
    MM(mh, nh); \
    __builtin_amdgcn_s_setprio(0); \
    __builtin_amdgcn_s_barrier(); \
  } while(0)

  STAGE_HALF(0,0,0); STAGE_HALF(0,1,1); STAGE_HALF(0,0,1); STAGE_HALF(0,1,0);
  STAGE_HALF(1,0,0); STAGE_HALF(1,1,1); STAGE_HALF(1,0,1);
  asm volatile("s_waitcnt vmcnt(6)" ::: "memory");
  __builtin_amdgcn_s_barrier();

  for (int j = 0; j < 15; ++j) {
    const int a = 2*j, b = 2*j+1;
    PH(0, 0,0, 1,1, STAGE_HALF(b,  1,0), (void)0);
    PH(0, 0,1, 0,1, STAGE_HALF(a+2,0,0), (void)0);
    PH(0, 1,1, 1,0, STAGE_HALF(a+2,1,1), (void)0);
    PH(0, 1,0, 0,1, STAGE_HALF(a+2,0,1), VM6);
    PH(1, 0,0, 1,1, STAGE_HALF(a+2,1,0), (void)0);
    PH(1, 0,1, 0,1, STAGE_HALF(b+2,0,0), (void)0);
    PH(1, 1,1, 1,0, STAGE_HALF(b+2,1,1), (void)0);
    PH(1, 1,0, 0,1, STAGE_HALF(b+2,0,1), VM6);
  }
  PH(0, 0,0, 1,1, STAGE_HALF(31,1,0), (void)0);
  PH(0, 0,1, 0,1, (void)0, (void)0);
  PH(0, 1,1, 1,0, (void)0, (void)0);
  PH(0, 1,0, 0,1, (void)0, VM0);
  PH(1, 0,0, 1,1, (void)0, (void)0);
  PH(1, 0,1, 0,1, (void)0, (void)0);
  PH(1, 1,1, 1,0, (void)0, (void)0);
  PH(1, 1,0, 0,1, (void)0, (void)0);

#undef PH
#undef VM6
#undef VM0
#undef MM
#undef LD_B
#undef LD_A
#undef STAGE_HALF

  // ---- coalesced epilogue: acc -> LDS (f16, stride 264) -> f16x8 stores ----
  {
    const int rowg0 = bm*256, colg0 = bn*256;
    const int rr = tid >> 2, cb = (tid & 3) * 64;
#pragma unroll
    for (int mh=0; mh<2; ++mh){
      __syncthreads();
#pragma unroll
      for (int mf=0; mf<4; ++mf)
#pragma unroll
      for (int nh=0; nh<2; ++nh)
#pragma unroll
      for (int nf=0; nf<2; ++nf){
        const int rl = wm*64 + mf*16 + fq*4;
        const int cl = nh*128 + wn*32 + nf*16 + fr;
        const float bs = bias[colg0 + cl];
#pragma unroll
        for (int q=0;q<4;++q)
          lds[(rl+q)*264 + cl] = f2h_bits(acc[mh*4+mf][nh*2+nf][q] + bs);
      }
      __syncthreads();
#pragma unroll
      for (int i=0;i<8;++i){
        f16x8 vv = *(const f16x8*)&lds[rr*264 + cb + i*8];
        *(f16x8*)&C[(size_t)(rowg0 + mh*128 + rr)*DH + colg0 + cb + i*8] = vv;
      }
    }
  }
}

// ---------------- 128^2 2-phase GEMM body (skip GEMM) ----------------
template<bool F16OUT>
__device__ __forceinline__ void gemm_body(
    const unsigned short* __restrict__ A,
    const unsigned short* __restrict__ B,
    const float* __restrict__ bias1,
    const float* __restrict__ bias2,
    void* __restrict__ Cout,
    int N, int Kd)
{
  __shared__ unsigned short lA[2][128*32];
  __shared__ unsigned short lB[2][128*32];
  const int tid  = threadIdx.x;
  const int lane = tid & 63;
  const int wv   = tid >> 6;
  const int bm   = blockIdx.x, bn = blockIdx.y;
  const int wm   = wv >> 1, wn = wv & 1;

  f32x4 acc[4][4];
#pragma unroll
  for (int m=0;m<4;m++)
#pragma unroll
    for (int n=0;n<4;n++) acc[m][n] = (f32x4){0.f,0.f,0.f,0.f};

  const int lr  = lane >> 2;
  const int kq4 = lane & 3;
  const unsigned short* gA = A + (size_t)(bm*128 + wv*16 + lr)*Kd + kq4*8;
  const unsigned short* gB = B + (size_t)(bn*128 + wv*16 + lr)*Kd + kq4*8;

#define STAGE(BUF, KS) do { \
    const int _ko = (KS)*32; \
    gload16(gA + _ko,                  &lA[BUF][wv*512]); \
    gload16(gA + _ko + (size_t)64*Kd,  &lA[BUF][2048 + wv*512]); \
    gload16(gB + _ko,                  &lB[BUF][wv*512]); \
    gload16(gB + _ko + (size_t)64*Kd,  &lB[BUF][2048 + wv*512]); \
  } while(0)

#define COMPUTE(BUF) do { \
    const int kq = (lane >> 4) * 8; \
    const int rr = lane & 15; \
    f16x8 af[4], bf[4]; \
    _Pragma("unroll") \
    for (int m=0;m<4;m++) \
      af[m] = *(const f16x8*)&lA[BUF][(wm*64 + m*16 + rr)*32 + kq]; \
    _Pragma("unroll") \
    for (int n=0;n<4;n++) \
      bf[n] = *(const f16x8*)&lB[BUF][(wn*64 + n*16 + rr)*32 + kq]; \
    _Pragma("unroll") \
    for (int m=0;m<4;m++) \
      _Pragma("unroll") \
      for (int n=0;n<4;n++) \
        acc[m][n] = __builtin_amdgcn_mfma_f32_16x16x32_f16(af[m], bf[n], acc[m][n], 0, 0, 0); \
  } while(0)

  STAGE(0, 0);
  __syncthreads();
  for (int e = 0; e < KSTEPS-2; e += 2) {
    STAGE(1, e+1); COMPUTE(0); __syncthreads();
    STAGE(0, e+2); COMPUTE(1); __syncthreads();
  }
  STAGE(1, KSTEPS-1); COMPUTE(0); __syncthreads();
  COMPUTE(1);

#undef STAGE
#undef COMPUTE

  const int rowBase = bm*128 + wm*64 + ((lane>>4)<<2);
  const int colBase = bn*128 + wn*64 + (lane & 15);
#pragma unroll
  for (int n=0;n<4;n++) {
    const int col = colBase + n*16;
    float bs = bias1[col];
    if (bias2) bs += bias2[col];
#pragma unroll
    for (int m=0;m<4;m++) {
#pragma unroll
      for (int q=0;q<4;q++) {
        const int row = rowBase + m*16 + q;
        float v = acc[m][n][q] + bs;
        if (F16OUT) ((unsigned short*)Cout)[(size_t)row*N + col] = f2h_bits(v);
        else        ((float*)Cout)[(size_t)row*N + col] = v;
      }
    }
  }
}

__global__ __launch_bounds__(256) void k_gemm_skip(
    const unsigned short* __restrict__ A, const unsigned short* __restrict__ B,
    const float* __restrict__ bias1, const float* __restrict__ bias2,
    void* __restrict__ Cout)
{
  gemm_body<false>(A, B, bias1, bias2, Cout, DO, DI);
}

// ---------------- exact top-64 per row ----------------
// R10: row staged in LDS (no register array -> no rule-#20 scratch risk);
// each pass streams usx8 chunks as short-lived vectors with fully-unrolled
// element access. Parallel scans (R7) + hist8 (R9) kept. Band recompute stays
// f64 (ref is f64-exact) with 4-way partial sums for FMA-latency hiding.
__global__ __launch_bounds__(256) void k_topk(
    const unsigned short* __restrict__ P,
    const float* __restrict__ X,
    const float* __restrict__ Wenc,
    const float* __restrict__ benc,
    int*   __restrict__ candIdx,
    float* __restrict__ candVal)
{
  __shared__ unsigned short rowl[DH];      // 32 KB
  __shared__ unsigned int hist8[8][256];
  __shared__ unsigned int hist2[256];
  __shared__ int   inIdx[64];
  __shared__ float inVal[64];
  __shared__ int    bandIdx[BCAP];
  __shared__ double bandVal[BCAP];
  __shared__ int s_inCnt, s_bandCnt, s_sel, s_above, s_sel2;

  const int r = blockIdx.x;
  const int tid = threadIdx.x;
  const int wv = tid >> 6, lane = tid & 63;
  const int lc = lane & 7;
  const unsigned short* Prow = P + (size_t)r*DH;

  for (int k=0;k<8;k++)
    ((usx8*)rowl)[tid + k*256] = ((const usx8*)Prow)[tid + k*256];
#pragma unroll
  for (int k=0;k<8;k++) hist8[k][tid] = 0;
  hist2[tid] = 0;
  if (tid==0){ s_inCnt=0; s_bandCnt=0; }
  __syncthreads();

  // pass 1: high-byte histogram of order-mapped u16
  for (int k=0;k<8;k++){
    usx8 c = ((const usx8*)rowl)[tid + k*256];
#pragma unroll
    for (int e=0;e<8;e++){
      unsigned short b = c[e];
      unsigned short o = (b & 0x8000) ? (unsigned short)~b : (unsigned short)(b|0x8000);
      atomicAdd(&hist8[lc][o>>8], 1u);
    }
  }
  __syncthreads();
  {
    unsigned int hs = 0;
#pragma unroll
    for (int c=0;c<8;c++) hs += hist8[c][tid];
    hist8[0][tid] = hs;
  }
  __syncthreads();

  // wave-parallel top-down scan: bucket where cum-from-top crosses KSEL
  if (tid < 64) {
    const int h0 = 255 - 4*tid;
    unsigned int c0=hist8[0][h0], c1=hist8[0][h0-1], c2=hist8[0][h0-2], c3=hist8[0][h0-3];
    unsigned int s = c0+c1+c2+c3;
    unsigned int Pi = s;
#pragma unroll
    for (int off=1; off<64; off<<=1){
      unsigned int t = __shfl_up(Pi, off);
      if (tid >= off) Pi += t;
    }
    unsigned long long mk = __ballot(Pi >= KSEL);
    int cr = (int)__builtin_ctzll(mk);
    if (tid == cr){
      unsigned int cum = Pi - s;
      unsigned int cc[4] = {c0,c1,c2,c3};
#pragma unroll
      for (int j=0;j<4;j++){
        if (cum + cc[j] >= KSEL){ s_sel = h0-j; s_above = (int)cum; break; }
        cum += cc[j];
      }
    }
  }
  __syncthreads();
  const int bsel = s_sel; const int cntAbove = s_above;

  // pass 2: low-byte histogram within the selected bucket
  for (int k=0;k<8;k++){
    usx8 c = ((const usx8*)rowl)[tid + k*256];
#pragma unroll
    for (int e=0;e<8;e++){
      unsigned short b = c[e];
      unsigned short o = (b & 0x8000) ? (unsigned short)~b : (unsigned short)(b|0x8000);
      if ((int)(o>>8) == bsel) atomicAdd(&hist2[o & 0xff], 1u);
    }
  }
  __syncthreads();
  {
    const int K2 = KSEL - cntAbove;
    if (tid < 64) {
      const int h0 = 255 - 4*tid;
      unsigned int c0=hist2[h0], c1=hist2[h0-1], c2=hist2[h0-2], c3=hist2[h0-3];
      unsigned int s = c0+c1+c2+c3;
      unsigned int Pi = s;
#pragma unroll
      for (int off=1; off<64; off<<=1){
        unsigned int t = __shfl_up(Pi, off);
        if (tid >= off) Pi += t;
      }
      unsigned long long mk = __ballot(Pi >= (unsigned)K2);
      int cr = (int)__builtin_ctzll(mk);
      if (tid == cr){
        unsigned int cum = Pi - s;
        unsigned int cc[4] = {c0,c1,c2,c3};
#pragma unroll
        for (int j=0;j<4;j++){
          if (cum + cc[j] >= (unsigned)K2){ s_sel2 = h0-j; break; }
          cum += cc[j];
        }
      }
    }
  }
  __syncthreads();

  unsigned short To = (unsigned short)((bsel<<8) | s_sel2);
  unsigned short tb = (To & 0x8000) ? (unsigned short)(To ^ 0x8000) : (unsigned short)~To;
  const float T = h_bits2f(tb);
  const float hiv = T + 2.0f*EPS_SEL, lov = T - 2.0f*EPS_SEL;

  // extraction: certain-in + ambiguous band
  for (int k=0;k<8;k++){
    usx8 c = ((const usx8*)rowl)[tid + k*256];
#pragma unroll
    for (int e=0;e<8;e++){
      unsigned short b = c[e];
      float v = h_bits2f(b);
      if (v > hiv){
        int p = atomicAdd(&s_inCnt,1);
        if (p < 64){ inIdx[p] = (tid + k*256)*8 + e; inVal[p] = v; }
      } else if (v >= lov){
        int p = atomicAdd(&s_bandCnt,1);
        if (p < BCAP) bandIdx[p] = (tid + k*256)*8 + e;
      }
    }
  }
  __syncthreads();
  const int m = s_inCnt < 64 ? s_inCnt : 64;
  const int B = s_bandCnt < BCAP ? s_bandCnt : BCAP;

  // exact f64 recompute for ambiguous band (4-way ILP partial sums)
  const float* Xr = X + (size_t)r*DI;
  for (int b=wv; b<B; b+=4){
    const int j = bandIdx[b];
    const float* Wr = Wenc + (size_t)j*DI;
    double s0=0.0, s1=0.0, s2=0.0, s3=0.0;
    for (int k0=lane; k0<DI; k0+=256){
      s0 = fma((double)Xr[k0],     (double)Wr[k0],     s0);
      s1 = fma((double)Xr[k0+64],  (double)Wr[k0+64],  s1);
      s2 = fma((double)Xr[k0+128], (double)Wr[k0+128], s2);
      s3 = fma((double)Xr[k0+192], (double)Wr[k0+192], s3);
    }
    double s = (s0+s1)+(s2+s3);
#pragma unroll
    for (int off=32; off>=1; off>>=1) s += __shfl_down(s, off);
    if (lane==0) bandVal[b] = s + (double)benc[j];
  }
  __syncthreads();

  int* ci = candIdx + (size_t)r*KSEL;
  float* cv = candVal + (size_t)r*KSEL;
  for (int t=tid; t<m; t+=256){ ci[t]=inIdx[t]; cv[t]=inVal[t]; }

  const int need = KSEL - m;
  if (tid < 64 && need > 0){
    unsigned int used = 0;
    for (int t=0;t<need;t++){
      double best = -1.0e300; int bi = -1;
#pragma unroll
      for (int sIt=0;sIt<4;sIt++){
        int b = tid + sIt*64;
        if (b < B && !((used>>sIt)&1)){
          double v = bandVal[b];
          if (v > best){ best=v; bi=b; }
        }
      }
#pragma unroll
      for (int off=32; off>=1; off>>=1){
        double ov = __shfl_down(best, off);
        int    oi = __shfl_down(bi,   off);
        if (ov > best){ best = ov; bi = oi; }
      }
      bi   = __shfl(bi, 0);
      best = __shfl(best, 0);
      if ((bi & 63) == tid) used |= 1u << (bi >> 6);
      if (tid == 0){
        ci[m+t] = bandIdx[bi];
        cv[m+t] = (float)best;
      }
    }
  }
}

// ---------------- sparse decode + loss partial ----------------
// R10: unconditional gathers (no `continue`) -> loads pipeline under vmcnt.
__global__ __launch_bounds__(256) void k_decode(
    float* __restrict__ outhat,
    const unsigned short* __restrict__ WdT,
    const int*   __restrict__ candIdx,
    const float* __restrict__ candVal,
    const float* __restrict__ target,
    float* __restrict__ lossPartial)
{
  __shared__ int   sIdx[KSEL];
  __shared__ float sVal[KSEL];
  __shared__ float wsum[4];
  const int r = blockIdx.x, tid = threadIdx.x;
  if (tid < KSEL){
    sIdx[tid]=candIdx[(size_t)r*KSEL+tid];
    float v=candVal[(size_t)r*KSEL+tid];
    sVal[tid] = v>0.f ? v : 0.f;
  }
  __syncthreads();
  float* orow = outhat + (size_t)r*DO;
  float a[8];
  {
    float4 v0 = *(const float4*)(orow + tid*8);
    float4 v1 = *(const float4*)(orow + tid*8 + 4);
    a[0]=v0.x;a[1]=v0.y;a[2]=v0.z;a[3]=v0.w;a[4]=v1.x;a[5]=v1.y;a[6]=v1.z;a[7]=v1.w;
  }
#pragma unroll 4
  for (int c=0;c<KSEL;c++){
    const float v = sVal[c];
    const f16x8 w = *(const f16x8*)(WdT + (size_t)sIdx[c]*DO + tid*8);
#pragma unroll
    for (int j=0;j<8;j++) a[j] = fmaf(v, (float)w[j], a[j]);
  }
  const float* trow = target + (size_t)r*DO;
  float4 t0 = *(const float4*)(trow + tid*8);
  float4 t1 = *(const float4*)(trow + tid*8 + 4);
  float tt[8] = {t0.x,t0.y,t0.z,t0.w,t1.x,t1.y,t1.z,t1.w};
  float ls = 0.f;
#pragma unroll
  for (int j=0;j<8;j++){ float d = a[j]-tt[j]; ls = fmaf(d,d,ls); }
  {
    float4 v0 = {a[0],a[1],a[2],a[3]}, v1 = {a[4],a[5],a[6],a[7]};
    *(float4*)(orow + tid*8) = v0;
    *(float4*)(orow + tid*8 + 4) = v1;
  }
#pragma unroll
  for (int off=32; off>=1; off>>=1) ls += __shfl_down(ls, off);
  if ((tid&63)==0) wsum[tid>>6]=ls;
  __syncthreads();
  if (tid==0)
    lossPartial[r] = (wsum[0]+wsum[1]+wsum[2]+wsum[3]) * (1.0f/((float)NT*(float)DO));
}

__global__ __launch_bounds__(256) void k_lossreduce(const float* __restrict__ lp,
                                                    float* __restrict__ out)
{
  __shared__ double ws[4];
  double s=0.0;
  for (int i=threadIdx.x;i<NT;i+=256) s += (double)lp[i];
#pragma unroll
  for (int off=32; off>=1; off>>=1) s += __shfl_down(s, off);
  if ((threadIdx.x&63)==0) ws[threadIdx.x>>6]=s;
  __syncthreads();
  if (threadIdx.x==0) *out = (float)(ws[0]+ws[1]+ws[2]+ws[3]);
}

// ---------------- finalize h: zero + scatter ----------------
__global__ __launch_bounds__(256) void k_scatter(
    float* __restrict__ H, const int* __restrict__ candIdx, const float* __restrict__ candVal)
{
  const int r=blockIdx.x, tid=threadIdx.x;
  float* hr = H + (size_t)r*DH;
  const float4 z = {0.f,0.f,0.f,0.f};
#pragma unroll
  for (int i=0;i<16;i++) ((float4*)hr)[tid + i*256] = z;
  __syncthreads();
  if (tid<KSEL){
    float v = candVal[(size_t)r*KSEL+tid];
    hr[candIdx[(size_t)r*KSEL+tid]] = v>0.f ? v : 0.f;
  }
}

extern "C" void kernel_launch(void* const* d_in, const int* in_sizes, int n_in,
                              void* d_out, int out_size, void* d_ws, size_t ws_size,
                              hipStream_t stream)
{
  const float* X     = (const float*)d_in[0];
  const float* tgt   = (const float*)d_in[1];
  const float* Wenc  = (const float*)d_in[2];
  const float* benc  = (const float*)d_in[3];
  const float* Wdec  = (const float*)d_in[4];
  const float* bdec  = (const float*)d_in[5];
  const float* Wskip = (const float*)d_in[6];
  const float* bskip = (const float*)d_in[7];

  float* out     = (float*)d_out;
  float* outhat  = out;
  float* H       = out + (size_t)NT*DO;
  float* lossOut = out + (size_t)NT*DO + (size_t)NT*DH;

  // h-region scratch plan (dead until k_scatter)
  char* hb = (char*)H;
  unsigned short* P      = (unsigned short*)hb;
  char* U                = hb + (size_t)NT*DH*2;
  unsigned short* Xh     = (unsigned short*)U;
  unsigned short* Wench  = (unsigned short*)(U + (size_t)NT*DI*2);
  unsigned short* Wskiph = (unsigned short*)(U + (size_t)NT*DI*2 + (size_t)DH*DI*2);
  unsigned short* WdTh   = (unsigned short*)(U + (size_t)NT*DI*2 + (size_t)DH*DI*2 + (size_t)DO*DI*2);

  int*   candIdx    = (int*)d_ws;
  float* candVal    = (float*)((char*)d_ws + (size_t)NT*KSEL*4);
  float* lossPartial= (float*)((char*)d_ws + (size_t)NT*KSEL*8);

  k_cvt<<<NT*DI/8/256, 256, 0, stream>>>(X, Xh, NT*DI/8);
  k_cvt<<<DH*DI/8/256, 256, 0, stream>>>(Wenc, Wench, DH*DI/8);
  k_cvt<<<DO*DI/8/256, 256, 0, stream>>>(Wskip, Wskiph, DO*DI/8);
  k_transpose_cvt<<<dim3(DO/64, DH/64), 256, 0, stream>>>(Wdec, WdTh);

  k_gemm_enc8<<<dim3(NT/256, DH/256), 512, 0, stream>>>(Xh, Wench, benc, P);
  k_topk<<<NT, 256, 0, stream>>>(P, X, Wenc, benc, candIdx, candVal);
  k_gemm_skip<<<dim3(NT/128, DO/128), 256, 0, stream>>>(Xh, Wskiph, bdec, bskip, (void*)outhat);
  k_decode<<<NT, 256, 0, stream>>>(outhat, WdTh, candIdx, candVal, tgt, lossPartial);
  k_lossreduce<<<1, 256, 0, stream>>>(lossPartial, lossOut);
  k_scatter<<<NT, 256, 0, stream>>>(H, candIdx, candVal);
}

// Round 12
// 1371.368 us; speedup vs baseline: 1.1073x; 1.0735x over previous
//
#include <hip/hip_runtime.h>
#include <stdint.h>

#define NT   8192
#define DI   2048
#define DH   16384
#define DO   2048
#define KSEL 64
#define EPS_SEL 0.004f
#define BCAP 256
#define KSTEPS 64   // K=2048 / BK=32 for the 128^2 skip GEMM

typedef _Float16 f16;
typedef f16  f16x8 __attribute__((ext_vector_type(8)));
typedef float f32x4 __attribute__((ext_vector_type(4)));
typedef unsigned short usx8 __attribute__((ext_vector_type(8)));

__device__ __forceinline__ unsigned short f2h_bits(float x){
  f16 h = (f16)x;
  union { f16 h; unsigned short u; } c; c.h = h; return c.u;
}
__device__ __forceinline__ float h_bits2f(unsigned short u){
  union { unsigned short u; f16 h; } c; c.u = u; return (float)c.h;
}

__device__ __forceinline__ void gload16(const void* g, void* lds){
  __builtin_amdgcn_global_load_lds(
    (const __attribute__((address_space(1))) void*)(uintptr_t)g,
    (__attribute__((address_space(3))) void*)(uint32_t)(uintptr_t)lds,
    16, 0, 0);
}

// ---------------- f32 -> f16 convert (vector8) ----------------
__global__ __launch_bounds__(256) void k_cvt(const float* __restrict__ in,
                                             unsigned short* __restrict__ out, int n8)
{
  int i = blockIdx.x*256 + threadIdx.x;
  if (i >= n8) return;
  const float4* p = (const float4*)in + (size_t)i*2;
  float4 a = p[0], b = p[1];
  union { f16 h[8]; usx8 u; } r;
  r.h[0]=(f16)a.x; r.h[1]=(f16)a.y; r.h[2]=(f16)a.z; r.h[3]=(f16)a.w;
  r.h[4]=(f16)b.x; r.h[5]=(f16)b.y; r.h[6]=(f16)b.z; r.h[7]=(f16)b.w;
  ((usx8*)out)[i] = r.u;
}

// ---------------- W_dec [DO][DH] f32 -> WdecT [DH][DO] f16 ----------------
__global__ __launch_bounds__(256) void k_transpose_cvt(const float* __restrict__ W,
                                                       unsigned short* __restrict__ WT)
{
  __shared__ unsigned short t[64][65];
  const int r0 = blockIdx.x*64;   // over DO
  const int c0 = blockIdx.y*64;   // over DH
  const int tid = threadIdx.x;
  const int q = tid >> 6, s = tid & 63;
#pragma unroll
  for (int i=0;i<16;i++){
    int r = q + i*4;
    t[r][s] = f2h_bits(W[(size_t)(r0+r)*DH + c0 + s]);
  }
  __syncthreads();
#pragma unroll
  for (int i=0;i<16;i++){
    int c = q + i*4;
    WT[(size_t)(c0+c)*DO + r0 + s] = t[s][c];
  }
}

// ================= 256^2 8-phase encoder GEMM (m201 template) =================
// R8-proven schedule + swizzle (conflicts = 0); R11: epilogue reverted to the
// R8/R9 direct stores (R10's LDS-staged epilogue was a measured regression).
__global__ __launch_bounds__(512, 2) void k_gemm_enc8(
    const unsigned short* __restrict__ Ap,
    const unsigned short* __restrict__ Bp,
    const float* __restrict__ bias,
    unsigned short* __restrict__ C)
{
  __shared__ unsigned short lds[65536];   // 128 KB
  const int tid  = threadIdx.x;
  const int lane = tid & 63;
  const int wv   = tid >> 6;
  const int wm   = wv >> 2;     // 0..1
  const int wn   = wv & 3;      // 0..3
  const int bm   = blockIdx.x;  // fastest -> B-panel reuse (R5-proven)
  const int bn   = blockIdx.y;
  const int fr   = lane & 15;
  const int fq   = lane >> 4;

  f32x4 acc[8][4];
#pragma unroll
  for (int i=0;i<8;i++)
#pragma unroll
    for (int j=0;j<4;j++) acc[i][j] = (f32x4){0.f,0.f,0.f,0.f};

  f16x8 ar[4][2];
  f16x8 br[2][2];

#define STAGE_HALF(t, ab, h) do { \
    const unsigned short* G_ = (ab) ? Bp : Ap; \
    const int rb_ = ((ab) ? bn : bm)*256 + (h)*128; \
    const int k0_ = (t)*64; \
    const int db_ = ((t)&1)*32768 + (ab)*16384 + (h)*8192; \
    _Pragma("unroll") \
    for (int is_=0; is_<2; ++is_){ \
      const int cw_ = wv*64 + is_*512; \
      const int cl_ = cw_ + lane; \
      const int cs_ = cl_ ^ ((cl_>>3)&7); \
      gload16(G_ + (size_t)(rb_ + (cs_>>3))*DI + k0_ + (cs_&7)*8, \
              (unsigned short*)lds + db_ + cw_*8); \
    } } while(0)

#define LD_A(buf, mh) do { \
    const int ba_ = (buf)*32768 + (mh)*8192; \
    _Pragma("unroll") \
    for (int mf_=0; mf_<4; ++mf_) \
    _Pragma("unroll") \
    for (int ks_=0; ks_<2; ++ks_){ \
      const int lin_ = (wm*64 + mf_*16 + fr)*128 + (ks_*4 + fq)*16; \
      const int sz_  = lin_ ^ ((((lin_>>7)&7))<<4); \
      ar[mf_][ks_] = *(const f16x8*)&lds[ba_ + (sz_>>1)]; \
    } } while(0)

#define LD_B(buf, nh) do { \
    const int bb_ = (buf)*32768 + 16384 + (nh)*8192; \
    _Pragma("unroll") \
    for (int nf_=0; nf_<2; ++nf_) \
    _Pragma("unroll") \
    for (int ks_=0; ks_<2; ++ks_){ \
      const int lin_ = (wn*32 + nf_*16 + fr)*128 + (ks_*4 + fq)*16; \
      const int sz_  = lin_ ^ ((((lin_>>7)&7))<<4); \
      br[nf_][ks_] = *(const f16x8*)&lds[bb_ + (sz_>>1)]; \
    } } while(0)

#define MM(mh, nh) do { \
    _Pragma("unroll") \
    for (int mf_=0; mf_<4; ++mf_) \
    _Pragma("unroll") \
    for (int nf_=0; nf_<2; ++nf_) \
    _Pragma("unroll") \
    for (int ks_=0; ks_<2; ++ks_) \
      acc[(mh)*4+mf_][(nh)*2+nf_] = __builtin_amdgcn_mfma_f32_16x16x32_f16( \
          ar[mf_][ks_], br[nf_][ks_], acc[(mh)*4+mf_][(nh)*2+nf_], 0, 0, 0); \
  } while(0)

#define VM6 asm volatile("s_waitcnt vmcnt(6)" ::: "memory")
#define VM0 asm volatile("s_waitcnt vmcnt(0)" ::: "memory")

#define PH(buf, mh, nh, LA_, LB_, STG, VM) do { \
    if (LA_) LD_A(buf, mh); \
    if (LB_) LD_B(buf, nh); \
    STG; \
    VM; \
    __builtin_amdgcn_s_barrier(); \
    asm volatile("s_waitcnt lgkmcnt(0)" ::: "memory"); \
    __builtin_amdgcn_sched_barrier(0); \
    __builtin_amdgcn_s_setprio(1); \
    MM(mh, nh); \
    __builtin_amdgcn_s_setprio(0); \
    __builtin_amdgcn_s_barrier(); \
  } while(0)

  STAGE_HALF(0,0,0); STAGE_HALF(0,1,1); STAGE_HALF(0,0,1); STAGE_HALF(0,1,0);
  STAGE_HALF(1,0,0); STAGE_HALF(1,1,1); STAGE_HALF(1,0,1);
  asm volatile("s_waitcnt vmcnt(6)" ::: "memory");
  __builtin_amdgcn_s_barrier();

  for (int j = 0; j < 15; ++j) {
    const int a = 2*j, b = 2*j+1;
    PH(0, 0,0, 1,1, STAGE_HALF(b,  1,0), (void)0);
    PH(0, 0,1, 0,1, STAGE_HALF(a+2,0,0), (void)0);
    PH(0, 1,1, 1,0, STAGE_HALF(a+2,1,1), (void)0);
    PH(0, 1,0, 0,1, STAGE_HALF(a+2,0,1), VM6);
    PH(1, 0,0, 1,1, STAGE_HALF(a+2,1,0), (void)0);
    PH(1, 0,1, 0,1, STAGE_HALF(b+2,0,0), (void)0);
    PH(1, 1,1, 1,0, STAGE_HALF(b+2,1,1), (void)0);
    PH(1, 1,0, 0,1, STAGE_HALF(b+2,0,1), VM6);
  }
  PH(0, 0,0, 1,1, STAGE_HALF(31,1,0), (void)0);
  PH(0, 0,1, 0,1, (void)0, (void)0);
  PH(0, 1,1, 1,0, (void)0, (void)0);
  PH(0, 1,0, 0,1, (void)0, VM0);
  PH(1, 0,0, 1,1, (void)0, (void)0);
  PH(1, 0,1, 0,1, (void)0, (void)0);
  PH(1, 1,1, 1,0, (void)0, (void)0);
  PH(1, 1,0, 0,1, (void)0, (void)0);

#undef PH
#undef VM6
#undef VM0
#undef MM
#undef LD_B
#undef LD_A
#undef STAGE_HALF

  // direct-store epilogue (R8/R9-proven)
#pragma unroll
  for (int nh=0; nh<2; ++nh)
#pragma unroll
  for (int nf=0; nf<2; ++nf){
    const int col = bn*256 + nh*128 + wn*32 + nf*16 + fr;
    const float bs = bias[col];
#pragma unroll
    for (int mh=0; mh<2; ++mh)
#pragma unroll
    for (int mf=0; mf<4; ++mf){
      const int row0 = bm*256 + mh*128 + wm*64 + mf*16 + fq*4;
#pragma unroll
      for (int q=0; q<4; ++q)
        C[(size_t)(row0+q)*DH + col] = f2h_bits(acc[mh*4+mf][nh*2+nf][q] + bs);
    }
  }
}

// ---------------- 128^2 2-phase GEMM body (skip GEMM) ----------------
template<bool F16OUT>
__device__ __forceinline__ void gemm_body(
    const unsigned short* __restrict__ A,
    const unsigned short* __restrict__ B,
    const float* __restrict__ bias1,
    const float* __restrict__ bias2,
    void* __restrict__ Cout,
    int N, int Kd)
{
  __shared__ unsigned short lA[2][128*32];
  __shared__ unsigned short lB[2][128*32];
  const int tid  = threadIdx.x;
  const int lane = tid & 63;
  const int wv   = tid >> 6;
  const int bm   = blockIdx.x, bn = blockIdx.y;
  const int wm   = wv >> 1, wn = wv & 1;

  f32x4 acc[4][4];
#pragma unroll
  for (int m=0;m<4;m++)
#pragma unroll
    for (int n=0;n<4;n++) acc[m][n] = (f32x4){0.f,0.f,0.f,0.f};

  const int lr  = lane >> 2;
  const int kq4 = lane & 3;
  const unsigned short* gA = A + (size_t)(bm*128 + wv*16 + lr)*Kd + kq4*8;
  const unsigned short* gB = B + (size_t)(bn*128 + wv*16 + lr)*Kd + kq4*8;

#define STAGE(BUF, KS) do { \
    const int _ko = (KS)*32; \
    gload16(gA + _ko,                  &lA[BUF][wv*512]); \
    gload16(gA + _ko + (size_t)64*Kd,  &lA[BUF][2048 + wv*512]); \
    gload16(gB + _ko,                  &lB[BUF][wv*512]); \
    gload16(gB + _ko + (size_t)64*Kd,  &lB[BUF][2048 + wv*512]); \
  } while(0)

#define COMPUTE(BUF) do { \
    const int kq = (lane >> 4) * 8; \
    const int rr = lane & 15; \
    f16x8 af[4], bf[4]; \
    _Pragma("unroll") \
    for (int m=0;m<4;m++) \
      af[m] = *(const f16x8*)&lA[BUF][(wm*64 + m*16 + rr)*32 + kq]; \
    _Pragma("unroll") \
    for (int n=0;n<4;n++) \
      bf[n] = *(const f16x8*)&lB[BUF][(wn*64 + n*16 + rr)*32 + kq]; \
    _Pragma("unroll") \
    for (int m=0;m<4;m++) \
      _Pragma("unroll") \
      for (int n=0;n<4;n++) \
        acc[m][n] = __builtin_amdgcn_mfma_f32_16x16x32_f16(af[m], bf[n], acc[m][n], 0, 0, 0); \
  } while(0)

  STAGE(0, 0);
  __syncthreads();
  for (int e = 0; e < KSTEPS-2; e += 2) {
    STAGE(1, e+1); COMPUTE(0); __syncthreads();
    STAGE(0, e+2); COMPUTE(1); __syncthreads();
  }
  STAGE(1, KSTEPS-1); COMPUTE(0); __syncthreads();
  COMPUTE(1);

#undef STAGE
#undef COMPUTE

  const int rowBase = bm*128 + wm*64 + ((lane>>4)<<2);
  const int colBase = bn*128 + wn*64 + (lane & 15);
#pragma unroll
  for (int n=0;n<4;n++) {
    const int col = colBase + n*16;
    float bs = bias1[col];
    if (bias2) bs += bias2[col];
#pragma unroll
    for (int m=0;m<4;m++) {
#pragma unroll
      for (int q=0;q<4;q++) {
        const int row = rowBase + m*16 + q;
        float v = acc[m][n][q] + bs;
        if (F16OUT) ((unsigned short*)Cout)[(size_t)row*N + col] = f2h_bits(v);
        else        ((float*)Cout)[(size_t)row*N + col] = v;
      }
    }
  }
}

__global__ __launch_bounds__(256) void k_gemm_skip(
    const unsigned short* __restrict__ A, const unsigned short* __restrict__ B,
    const float* __restrict__ bias1, const float* __restrict__ bias2,
    void* __restrict__ Cout)
{
  gemm_body<false>(A, B, bias1, bias2, Cout, DO, DI);
}

// ---------------- exact top-64 per row ----------------
// R11: row held in 8 NAMED usx8 registers (no array indexing -> no scratch);
// zero LDS row passes, LDS = atomics + small lists only (~12 KB -> better
// occupancy). hist copies padded to stride 257 so bank = (copy+bucket)%32 —
// a hot bucket's 8 copies land in 8 distinct banks (fixes R9's null: stride
// 256 put all copies of one bucket in the SAME bank).
__global__ __launch_bounds__(256) void k_topk(
    const unsigned short* __restrict__ P,
    const float* __restrict__ X,
    const float* __restrict__ Wenc,
    const float* __restrict__ benc,
    int*   __restrict__ candIdx,
    float* __restrict__ candVal)
{
  __shared__ unsigned int hist8[8][257];   // padded stride
  __shared__ unsigned int hist2[257];
  __shared__ int   inIdx[64];
  __shared__ float inVal[64];
  __shared__ int    bandIdx[BCAP];
  __shared__ double bandVal[BCAP];
  __shared__ int s_inCnt, s_bandCnt, s_sel, s_above, s_sel2;

  const int r = blockIdx.x;
  const int tid = threadIdx.x;
  const int wv = tid >> 6, lane = tid & 63;
  const int lc = lane & 7;
  const unsigned short* Prow = P + (size_t)r*DH;

#pragma unroll
  for (int k=0;k<8;k++) hist8[k][tid] = 0;
  hist2[tid] = 0;
  if (tid==0){ s_inCnt=0; s_bandCnt=0; }

  // row -> 8 named registers (32 VGPR)
  const usx8* Pv = (const usx8*)Prow;
  usx8 c0 = Pv[tid];        usx8 c1 = Pv[tid+256];
  usx8 c2 = Pv[tid+512];    usx8 c3 = Pv[tid+768];
  usx8 c4 = Pv[tid+1024];   usx8 c5 = Pv[tid+1280];
  usx8 c6 = Pv[tid+1536];   usx8 c7 = Pv[tid+1792];
  __syncthreads();

#define OMAP(b) (unsigned short)(((b) & 0x8000) ? (unsigned short)~(b) : (unsigned short)((b)|0x8000))
#define H1(CC) { _Pragma("unroll") for (int e=0;e<8;e++){ \
    unsigned short o = OMAP(CC[e]); atomicAdd(&hist8[lc][o>>8], 1u); } }
  H1(c0) H1(c1) H1(c2) H1(c3) H1(c4) H1(c5) H1(c6) H1(c7)
#undef H1
  __syncthreads();
  {
    unsigned int hs = 0;
#pragma unroll
    for (int c=0;c<8;c++) hs += hist8[c][tid];
    hist8[0][tid] = hs;
  }
  __syncthreads();

  // wave-parallel top-down scan: bucket where cum-from-top crosses KSEL
  if (tid < 64) {
    const int h0 = 255 - 4*tid;
    unsigned int c0_=hist8[0][h0], c1_=hist8[0][h0-1], c2_=hist8[0][h0-2], c3_=hist8[0][h0-3];
    unsigned int s = c0_+c1_+c2_+c3_;
    unsigned int Pi = s;
#pragma unroll
    for (int off=1; off<64; off<<=1){
      unsigned int t = __shfl_up(Pi, off);
      if (tid >= off) Pi += t;
    }
    unsigned long long mk = __ballot(Pi >= KSEL);
    int cr = (int)__builtin_ctzll(mk);
    if (tid == cr){
      unsigned int cum = Pi - s;
      unsigned int cc[4] = {c0_,c1_,c2_,c3_};
#pragma unroll
      for (int j=0;j<4;j++){
        if (cum + cc[j] >= KSEL){ s_sel = h0-j; s_above = (int)cum; break; }
        cum += cc[j];
      }
    }
  }
  __syncthreads();
  const int bsel = s_sel; const int cntAbove = s_above;

#define H2(CC) { _Pragma("unroll") for (int e=0;e<8;e++){ \
    unsigned short o = OMAP(CC[e]); \
    if ((int)(o>>8) == bsel) atomicAdd(&hist2[o & 0xff], 1u); } }
  H2(c0) H2(c1) H2(c2) H2(c3) H2(c4) H2(c5) H2(c6) H2(c7)
#undef H2
  __syncthreads();
  {
    const int K2 = KSEL - cntAbove;
    if (tid < 64) {
      const int h0 = 255 - 4*tid;
      unsigned int c0_=hist2[h0], c1_=hist2[h0-1], c2_=hist2[h0-2], c3_=hist2[h0-3];
      unsigned int s = c0_+c1_+c2_+c3_;
      unsigned int Pi = s;
#pragma unroll
      for (int off=1; off<64; off<<=1){
        unsigned int t = __shfl_up(Pi, off);
        if (tid >= off) Pi += t;
      }
      unsigned long long mk = __ballot(Pi >= (unsigned)K2);
      int cr = (int)__builtin_ctzll(mk);
      if (tid == cr){
        unsigned int cum = Pi - s;
        unsigned int cc[4] = {c0_,c1_,c2_,c3_};
#pragma unroll
        for (int j=0;j<4;j++){
          if (cum + cc[j] >= (unsigned)K2){ s_sel2 = h0-j; break; }
          cum += cc[j];
        }
      }
    }
  }
  __syncthreads();

  unsigned short To = (unsigned short)((bsel<<8) | s_sel2);
  unsigned short tb = (To & 0x8000) ? (unsigned short)(To ^ 0x8000) : (unsigned short)~To;
  const float T = h_bits2f(tb);
  const float hiv = T + 2.0f*EPS_SEL, lov = T - 2.0f*EPS_SEL;

#define EXT(CC, KK) { _Pragma("unroll") for (int e=0;e<8;e++){ \
    float v = h_bits2f(CC[e]); \
    if (v > hiv){ \
      int p = atomicAdd(&s_inCnt,1); \
      if (p < 64){ inIdx[p] = (tid + (KK)*256)*8 + e; inVal[p] = v; } \
    } else if (v >= lov){ \
      int p = atomicAdd(&s_bandCnt,1); \
      if (p < BCAP) bandIdx[p] = (tid + (KK)*256)*8 + e; \
    } } }
  EXT(c0,0) EXT(c1,1) EXT(c2,2) EXT(c3,3) EXT(c4,4) EXT(c5,5) EXT(c6,6) EXT(c7,7)
#undef EXT
#undef OMAP
  __syncthreads();
  const int m = s_inCnt < 64 ? s_inCnt : 64;
  const int B = s_bandCnt < BCAP ? s_bandCnt : BCAP;

  // exact f64 recompute for ambiguous band (4-way ILP partial sums)
  const float* Xr = X + (size_t)r*DI;
  for (int b=wv; b<B; b+=4){
    const int j = bandIdx[b];
    const float* Wr = Wenc + (size_t)j*DI;
    double s0=0.0, s1=0.0, s2=0.0, s3=0.0;
    for (int k0=lane; k0<DI; k0+=256){
      s0 = fma((double)Xr[k0],     (double)Wr[k0],     s0);
      s1 = fma((double)Xr[k0+64],  (double)Wr[k0+64],  s1);
      s2 = fma((double)Xr[k0+128], (double)Wr[k0+128], s2);
      s3 = fma((double)Xr[k0+192], (double)Wr[k0+192], s3);
    }
    double s = (s0+s1)+(s2+s3);
#pragma unroll
    for (int off=32; off>=1; off>>=1) s += __shfl_down(s, off);
    if (lane==0) bandVal[b] = s + (double)benc[j];
  }
  __syncthreads();

  int* ci = candIdx + (size_t)r*KSEL;
  float* cv = candVal + (size_t)r*KSEL;
  for (int t=tid; t<m; t+=256){ ci[t]=inIdx[t]; cv[t]=inVal[t]; }

  const int need = KSEL - m;
  if (tid < 64 && need > 0){
    unsigned int used = 0;
    for (int t=0;t<need;t++){
      double best = -1.0e300; int bi = -1;
#pragma unroll
      for (int sIt=0;sIt<4;sIt++){
        int b = tid + sIt*64;
        if (b < B && !((used>>sIt)&1)){
          double v = bandVal[b];
          if (v > best){ best=v; bi=b; }
        }
      }
#pragma unroll
      for (int off=32; off>=1; off>>=1){
        double ov = __shfl_down(best, off);
        int    oi = __shfl_down(bi,   off);
        if (ov > best){ best = ov; bi = oi; }
      }
      bi   = __shfl(bi, 0);
      best = __shfl(best, 0);
      if ((bi & 63) == tid) used |= 1u << (bi >> 6);
      if (tid == 0){
        ci[m+t] = bandIdx[bi];
        cv[m+t] = (float)best;
      }
    }
  }
}

// ---------------- sparse decode + loss partial ----------------
__global__ __launch_bounds__(256) void k_decode(
    float* __restrict__ outhat,
    const unsigned short* __restrict__ WdT,
    const int*   __restrict__ candIdx,
    const float* __restrict__ candVal,
    const float* __restrict__ target,
    float* __restrict__ lossPartial)
{
  __shared__ int   sIdx[KSEL];
  __shared__ float sVal[KSEL];
  __shared__ float wsum[4];
  const int r = blockIdx.x, tid = threadIdx.x;
  if (tid < KSEL){
    sIdx[tid]=candIdx[(size_t)r*KSEL+tid];
    float v=candVal[(size_t)r*KSEL+tid];
    sVal[tid] = v>0.f ? v : 0.f;
  }
  __syncthreads();
  float* orow = outhat + (size_t)r*DO;
  float a[8];
  {
    float4 v0 = *(const float4*)(orow + tid*8);
    float4 v1 = *(const float4*)(orow + tid*8 + 4);
    a[0]=v0.x;a[1]=v0.y;a[2]=v0.z;a[3]=v0.w;a[4]=v1.x;a[5]=v1.y;a[6]=v1.z;a[7]=v1.w;
  }
#pragma unroll 4
  for (int c=0;c<KSEL;c++){
    const float v = sVal[c];
    const f16x8 w = *(const f16x8*)(WdT + (size_t)sIdx[c]*DO + tid*8);
#pragma unroll
    for (int j=0;j<8;j++) a[j] = fmaf(v, (float)w[j], a[j]);
  }
  const float* trow = target + (size_t)r*DO;
  float4 t0 = *(const float4*)(trow + tid*8);
  float4 t1 = *(const float4*)(trow + tid*8 + 4);
  float tt[8] = {t0.x,t0.y,t0.z,t0.w,t1.x,t1.y,t1.z,t1.w};
  float ls = 0.f;
#pragma unroll
  for (int j=0;j<8;j++){ float d = a[j]-tt[j]; ls = fmaf(d,d,ls); }
  {
    float4 v0 = {a[0],a[1],a[2],a[3]}, v1 = {a[4],a[5],a[6],a[7]};
    *(float4*)(orow + tid*8) = v0;
    *(float4*)(orow + tid*8 + 4) = v1;
  }
#pragma unroll
  for (int off=32; off>=1; off>>=1) ls += __shfl_down(ls, off);
  if ((tid&63)==0) wsum[tid>>6]=ls;
  __syncthreads();
  if (tid==0)
    lossPartial[r] = (wsum[0]+wsum[1]+wsum[2]+wsum[3]) * (1.0f/((float)NT*(float)DO));
}

__global__ __launch_bounds__(256) void k_lossreduce(const float* __restrict__ lp,
                                                    float* __restrict__ out)
{
  __shared__ double ws[4];
  double s=0.0;
  for (int i=threadIdx.x;i<NT;i+=256) s += (double)lp[i];
#pragma unroll
  for (int off=32; off>=1; off>>=1) s += __shfl_down(s, off);
  if ((threadIdx.x&63)==0) ws[threadIdx.x>>6]=s;
  __syncthreads();
  if (threadIdx.x==0) *out = (float)(ws[0]+ws[1]+ws[2]+ws[3]);
}

// ---------------- finalize h: zero + scatter ----------------
__global__ __launch_bounds__(256) void k_scatter(
    float* __restrict__ H, const int* __restrict__ candIdx, const float* __restrict__ candVal)
{
  const int r=blockIdx.x, tid=threadIdx.x;
  float* hr = H + (size_t)r*DH;
  const float4 z = {0.f,0.f,0.f,0.f};
#pragma unroll
  for (int i=0;i<16;i++) ((float4*)hr)[tid + i*256] = z;
  __syncthreads();
  if (tid<KSEL){
    float v = candVal[(size_t)r*KSEL+tid];
    hr[candIdx[(size_t)r*KSEL+tid]] = v>0.f ? v : 0.f;
  }
}

extern "C" void kernel_launch(void* const* d_in, const int* in_sizes, int n_in,
                              void* d_out, int out_size, void* d_ws, size_t ws_size,
                              hipStream_t stream)
{
  const float* X     = (const float*)d_in[0];
  const float* tgt   = (const float*)d_in[1];
  const float* Wenc  = (const float*)d_in[2];
  const float* benc  = (const float*)d_in[3];
  const float* Wdec  = (const float*)d_in[4];
  const float* bdec  = (const float*)d_in[5];
  const float* Wskip = (const float*)d_in[6];
  const float* bskip = (const float*)d_in[7];

  float* out     = (float*)d_out;
  float* outhat  = out;
  float* H       = out + (size_t)NT*DO;
  float* lossOut = out + (size_t)NT*DO + (size_t)NT*DH;

  // h-region scratch plan (dead until k_scatter)
  char* hb = (char*)H;
  unsigned short* P      = (unsigned short*)hb;
  char* U                = hb + (size_t)NT*DH*2;
  unsigned short* Xh     = (unsigned short*)U;
  unsigned short* Wench  = (unsigned short*)(U + (size_t)NT*DI*2);
  unsigned short* Wskiph = (unsigned short*)(U + (size_t)NT*DI*2 + (size_t)DH*DI*2);
  unsigned short* WdTh   = (unsigned short*)(U + (size_t)NT*DI*2 + (size_t)DH*DI*2 + (size_t)DO*DI*2);

  int*   candIdx    = (int*)d_ws;
  float* candVal    = (float*)((char*)d_ws + (size_t)NT*KSEL*4);
  float* lossPartial= (float*)((char*)d_ws + (size_t)NT*KSEL*8);

  k_cvt<<<NT*DI/8/256, 256, 0, stream>>>(X, Xh, NT*DI/8);
  k_cvt<<<DH*DI/8/256, 256, 0, stream>>>(Wenc, Wench, DH*DI/8);
  k_cvt<<<DO*DI/8/256, 256, 0, stream>>>(Wskip, Wskiph, DO*DI/8);
  k_transpose_cvt<<<dim3(DO/64, DH/64), 256, 0, stream>>>(Wdec, WdTh);

  k_gemm_enc8<<<dim3(NT/256, DH/256), 512, 0, stream>>>(Xh, Wench, benc, P);
  k_topk<<<NT, 256, 0, stream>>>(P, X, Wenc, benc, candIdx, candVal);
  k_gemm_skip<<<dim3(NT/128, DO/128), 256, 0, stream>>>(Xh, Wskiph, bdec, bskip, (void*)outhat);
  k_decode<<<NT, 256, 0, stream>>>(outhat, WdTh, candIdx, candVal, tgt, lossPartial);
  k_lossreduce<<<1, 256, 0, stream>>>(lossPartial, lossOut);
  k_scatter<<<NT, 256, 0, stream>>>(H, candIdx, candVal);
}

// Round 13
// 1195.337 us; speedup vs baseline: 1.2704x; 1.1473x over previous
//
#include <hip/hip_runtime.h>
#include <stdint.h>

#define NT   8192
#define DI   2048
#define DH   16384
#define DO   2048
#define KSEL 64
#define EPS_SEL 0.004f
#define BCAP 256
#define KSTEPS 64   // K=2048 / BK=32 for the 128^2 skip GEMM

typedef _Float16 f16;
typedef f16  f16x8 __attribute__((ext_vector_type(8)));
typedef float f32x4 __attribute__((ext_vector_type(4)));
typedef unsigned short usx8 __attribute__((ext_vector_type(8)));

__device__ __forceinline__ unsigned short f2h_bits(float x){
  f16 h = (f16)x;
  union { f16 h; unsigned short u; } c; c.h = h; return c.u;
}
__device__ __forceinline__ float h_bits2f(unsigned short u){
  union { unsigned short u; f16 h; } c; c.u = u; return (float)c.h;
}
__device__ __forceinline__ unsigned char f2fp8(float x){
  return (unsigned char)(__builtin_amdgcn_cvt_pk_fp8_f32(x, 0.f, 0u, false) & 0xff);
}

__device__ __forceinline__ void gload16(const void* g, void* lds){
  __builtin_amdgcn_global_load_lds(
    (const __attribute__((address_space(1))) void*)(uintptr_t)g,
    (__attribute__((address_space(3))) void*)(uint32_t)(uintptr_t)lds,
    16, 0, 0);
}

// ---------------- f32 -> f16 convert (vector8) ----------------
__global__ __launch_bounds__(256) void k_cvt(const float* __restrict__ in,
                                             unsigned short* __restrict__ out, int n8)
{
  int i = blockIdx.x*256 + threadIdx.x;
  if (i >= n8) return;
  const float4* p = (const float4*)in + (size_t)i*2;
  float4 a = p[0], b = p[1];
  union { f16 h[8]; usx8 u; } r;
  r.h[0]=(f16)a.x; r.h[1]=(f16)a.y; r.h[2]=(f16)a.z; r.h[3]=(f16)a.w;
  r.h[4]=(f16)b.x; r.h[5]=(f16)b.y; r.h[6]=(f16)b.z; r.h[7]=(f16)b.w;
  ((usx8*)out)[i] = r.u;
}

// -------- W_dec [DO][DH] f32 -> WdecT8 [DH][DO] fp8 e4m3, pre-scaled x64 -----
// |W_dec| <= sqrt(1/16384) = 1/128; x64 -> [-0.5, 0.5], e4m3 normal range
// (rel err <= 6.25%). Decode multiplies by v/64.
__global__ __launch_bounds__(256) void k_transpose_cvt8(const float* __restrict__ W,
                                                        unsigned char* __restrict__ WT)
{
  __shared__ unsigned char t[64][68];
  const int r0 = blockIdx.x*64;   // over DO
  const int c0 = blockIdx.y*64;   // over DH
  const int tid = threadIdx.x;
  const int q = tid >> 6, s = tid & 63;
#pragma unroll
  for (int i=0;i<16;i++){
    int r = q + i*4;
    t[r][s] = f2fp8(W[(size_t)(r0+r)*DH + c0 + s] * 64.0f);
  }
  __syncthreads();
#pragma unroll
  for (int i=0;i<16;i++){
    int c = q + i*4;
    WT[(size_t)(c0+c)*DO + r0 + s] = t[s][c];
  }
}

// ================= 256^2 8-phase encoder GEMM (m201 template) =================
// R8-proven swizzle (conflicts = 0). R12: SINGLE barrier per phase (closing
// barrier removed). Cycle model: 2-barrier lockstep alternates LDS(~670cy) and
// MFMA(~620cy) -> 48% util (measured 47%). With one barrier, a wave past
// MFMA(k) issues ds_read(k+1) while others still MFMA(k) -> overlap; drift
// bounded to 1 phase. Safety: every STAGE targets a half last-read >=1 phase
// earlier across a barrier; global_load_lds write lands >=600cy after issue
// vs racing read completing <=200cy after the barrier. VM6 ledger unchanged.
__global__ __launch_bounds__(512, 2) void k_gemm_enc8(
    const unsigned short* __restrict__ Ap,
    const unsigned short* __restrict__ Bp,
    const float* __restrict__ bias,
    unsigned short* __restrict__ C)
{
  __shared__ unsigned short lds[65536];   // 128 KB
  const int tid  = threadIdx.x;
  const int lane = tid & 63;
  const int wv   = tid >> 6;
  const int wm   = wv >> 2;     // 0..1
  const int wn   = wv & 3;      // 0..3
  const int bm   = blockIdx.x;  // fastest -> B-panel reuse (R5-proven)
  const int bn   = blockIdx.y;
  const int fr   = lane & 15;
  const int fq   = lane >> 4;

  f32x4 acc[8][4];
#pragma unroll
  for (int i=0;i<8;i++)
#pragma unroll
    for (int j=0;j<4;j++) acc[i][j] = (f32x4){0.f,0.f,0.f,0.f};

  f16x8 ar[4][2];
  f16x8 br[2][2];

#define STAGE_HALF(t, ab, h) do { \
    const unsigned short* G_ = (ab) ? Bp : Ap; \
    const int rb_ = ((ab) ? bn : bm)*256 + (h)*128; \
    const int k0_ = (t)*64; \
    const int db_ = ((t)&1)*32768 + (ab)*16384 + (h)*8192; \
    _Pragma("unroll") \
    for (int is_=0; is_<2; ++is_){ \
      const int cw_ = wv*64 + is_*512; \
      const int cl_ = cw_ + lane; \
      const int cs_ = cl_ ^ ((cl_>>3)&7); \
      gload16(G_ + (size_t)(rb_ + (cs_>>3))*DI + k0_ + (cs_&7)*8, \
              (unsigned short*)lds + db_ + cw_*8); \
    } } while(0)

#define LD_A(buf, mh) do { \
    const int ba_ = (buf)*32768 + (mh)*8192; \
    _Pragma("unroll") \
    for (int mf_=0; mf_<4; ++mf_) \
    _Pragma("unroll") \
    for (int ks_=0; ks_<2; ++ks_){ \
      const int lin_ = (wm*64 + mf_*16 + fr)*128 + (ks_*4 + fq)*16; \
      const int sz_  = lin_ ^ ((((lin_>>7)&7))<<4); \
      ar[mf_][ks_] = *(const f16x8*)&lds[ba_ + (sz_>>1)]; \
    } } while(0)

#define LD_B(buf, nh) do { \
    const int bb_ = (buf)*32768 + 16384 + (nh)*8192; \
    _Pragma("unroll") \
    for (int nf_=0; nf_<2; ++nf_) \
    _Pragma("unroll") \
    for (int ks_=0; ks_<2; ++ks_){ \
      const int lin_ = (wn*32 + nf_*16 + fr)*128 + (ks_*4 + fq)*16; \
      const int sz_  = lin_ ^ ((((lin_>>7)&7))<<4); \
      br[nf_][ks_] = *(const f16x8*)&lds[bb_ + (sz_>>1)]; \
    } } while(0)

#define MM(mh, nh) do { \
    _Pragma("unroll") \
    for (int mf_=0; mf_<4; ++mf_) \
    _Pragma("unroll") \
    for (int nf_=0; nf_<2; ++nf_) \
    _Pragma("unroll") \
    for (int ks_=0; ks_<2; ++ks_) \
      acc[(mh)*4+mf_][(nh)*2+nf_] = __builtin_amdgcn_mfma_f32_16x16x32_f16( \
          ar[mf_][ks_], br[nf_][ks_], acc[(mh)*4+mf_][(nh)*2+nf_], 0, 0, 0); \
  } while(0)

#define VM6 asm volatile("s_waitcnt vmcnt(6)" ::: "memory")
#define VM0 asm volatile("s_waitcnt vmcnt(0)" ::: "memory")

// single barrier per phase (R12)
#define PH(buf, mh, nh, LA_, LB_, STG, VM) do { \
    if (LA_) LD_A(buf, mh); \
    if (LB_) LD_B(buf, nh); \
    STG; \
    VM; \
    __builtin_amdgcn_s_barrier(); \
    asm volatile("s_waitcnt lgkmcnt(0)" ::: "memory"); \
    __builtin_amdgcn_sched_barrier(0); \
    __builtin_amdgcn_s_setprio(1); \
    MM(mh, nh); \
    __builtin_amdgcn_s_setprio(0); \
  } while(0)

  STAGE_HALF(0,0,0); STAGE_HALF(0,1,1); STAGE_HALF(0,0,1); STAGE_HALF(0,1,0);
  STAGE_HALF(1,0,0); STAGE_HALF(1,1,1); STAGE_HALF(1,0,1);
  asm volatile("s_waitcnt vmcnt(6)" ::: "memory");
  __builtin_amdgcn_s_barrier();

  for (int j = 0; j < 15; ++j) {
    const int a = 2*j, b = 2*j+1;
    PH(0, 0,0, 1,1, STAGE_HALF(b,  1,0), (void)0);
    PH(0, 0,1, 0,1, STAGE_HALF(a+2,0,0), (void)0);
    PH(0, 1,1, 1,0, STAGE_HALF(a+2,1,1), (void)0);
    PH(0, 1,0, 0,1, STAGE_HALF(a+2,0,1), VM6);
    PH(1, 0,0, 1,1, STAGE_HALF(a+2,1,0), (void)0);
    PH(1, 0,1, 0,1, STAGE_HALF(b+2,0,0), (void)0);
    PH(1, 1,1, 1,0, STAGE_HALF(b+2,1,1), (void)0);
    PH(1, 1,0, 0,1, STAGE_HALF(b+2,0,1), VM6);
  }
  PH(0, 0,0, 1,1, STAGE_HALF(31,1,0), (void)0);
  PH(0, 0,1, 0,1, (void)0, (void)0);
  PH(0, 1,1, 1,0, (void)0, (void)0);
  PH(0, 1,0, 0,1, (void)0, VM0);
  PH(1, 0,0, 1,1, (void)0, (void)0);
  PH(1, 0,1, 0,1, (void)0, (void)0);
  PH(1, 1,1, 1,0, (void)0, (void)0);
  PH(1, 1,0, 0,1, (void)0, (void)0);

#undef PH
#undef VM6
#undef VM0
#undef MM
#undef LD_B
#undef LD_A
#undef STAGE_HALF

  // direct-store epilogue (R8/R9-proven)
#pragma unroll
  for (int nh=0; nh<2; ++nh)
#pragma unroll
  for (int nf=0; nf<2; ++nf){
    const int col = bn*256 + nh*128 + wn*32 + nf*16 + fr;
    const float bs = bias[col];
#pragma unroll
    for (int mh=0; mh<2; ++mh)
#pragma unroll
    for (int mf=0; mf<4; ++mf){
      const int row0 = bm*256 + mh*128 + wm*64 + mf*16 + fq*4;
#pragma unroll
      for (int q=0; q<4; ++q)
        C[(size_t)(row0+q)*DH + col] = f2h_bits(acc[mh*4+mf][nh*2+nf][q] + bs);
    }
  }
}

// ---------------- 128^2 2-phase GEMM body (skip GEMM) ----------------
template<bool F16OUT>
__device__ __forceinline__ void gemm_body(
    const unsigned short* __restrict__ A,
    const unsigned short* __restrict__ B,
    const float* __restrict__ bias1,
    const float* __restrict__ bias2,
    void* __restrict__ Cout,
    int N, int Kd)
{
  __shared__ unsigned short lA[2][128*32];
  __shared__ unsigned short lB[2][128*32];
  const int tid  = threadIdx.x;
  const int lane = tid & 63;
  const int wv   = tid >> 6;
  const int bm   = blockIdx.x, bn = blockIdx.y;
  const int wm   = wv >> 1, wn = wv & 1;

  f32x4 acc[4][4];
#pragma unroll
  for (int m=0;m<4;m++)
#pragma unroll
    for (int n=0;n<4;n++) acc[m][n] = (f32x4){0.f,0.f,0.f,0.f};

  const int lr  = lane >> 2;
  const int kq4 = lane & 3;
  const unsigned short* gA = A + (size_t)(bm*128 + wv*16 + lr)*Kd + kq4*8;
  const unsigned short* gB = B + (size_t)(bn*128 + wv*16 + lr)*Kd + kq4*8;

#define STAGE(BUF, KS) do { \
    const int _ko = (KS)*32; \
    gload16(gA + _ko,                  &lA[BUF][wv*512]); \
    gload16(gA + _ko + (size_t)64*Kd,  &lA[BUF][2048 + wv*512]); \
    gload16(gB + _ko,                  &lB[BUF][wv*512]); \
    gload16(gB + _ko + (size_t)64*Kd,  &lB[BUF][2048 + wv*512]); \
  } while(0)

#define COMPUTE(BUF) do { \
    const int kq = (lane >> 4) * 8; \
    const int rr = lane & 15; \
    f16x8 af[4], bf[4]; \
    _Pragma("unroll") \
    for (int m=0;m<4;m++) \
      af[m] = *(const f16x8*)&lA[BUF][(wm*64 + m*16 + rr)*32 + kq]; \
    _Pragma("unroll") \
    for (int n=0;n<4;n++) \
      bf[n] = *(const f16x8*)&lB[BUF][(wn*64 + n*16 + rr)*32 + kq]; \
    _Pragma("unroll") \
    for (int m=0;m<4;m++) \
      _Pragma("unroll") \
      for (int n=0;n<4;n++) \
        acc[m][n] = __builtin_amdgcn_mfma_f32_16x16x32_f16(af[m], bf[n], acc[m][n], 0, 0, 0); \
  } while(0)

  STAGE(0, 0);
  __syncthreads();
  for (int e = 0; e < KSTEPS-2; e += 2) {
    STAGE(1, e+1); COMPUTE(0); __syncthreads();
    STAGE(0, e+2); COMPUTE(1); __syncthreads();
  }
  STAGE(1, KSTEPS-1); COMPUTE(0); __syncthreads();
  COMPUTE(1);

#undef STAGE
#undef COMPUTE

  const int rowBase = bm*128 + wm*64 + ((lane>>4)<<2);
  const int colBase = bn*128 + wn*64 + (lane & 15);
#pragma unroll
  for (int n=0;n<4;n++) {
    const int col = colBase + n*16;
    float bs = bias1[col];
    if (bias2) bs += bias2[col];
#pragma unroll
    for (int m=0;m<4;m++) {
#pragma unroll
      for (int q=0;q<4;q++) {
        const int row = rowBase + m*16 + q;
        float v = acc[m][n][q] + bs;
        if (F16OUT) ((unsigned short*)Cout)[(size_t)row*N + col] = f2h_bits(v);
        else        ((float*)Cout)[(size_t)row*N + col] = v;
      }
    }
  }
}

__global__ __launch_bounds__(256) void k_gemm_skip(
    const unsigned short* __restrict__ A, const unsigned short* __restrict__ B,
    const float* __restrict__ bias1, const float* __restrict__ bias2,
    void* __restrict__ Cout)
{
  gemm_body<false>(A, B, bias1, bias2, Cout, DO, DI);
}

// ---------------- exact top-64 per row (R11-proven) ----------------
__global__ __launch_bounds__(256) void k_topk(
    const unsigned short* __restrict__ P,
    const float* __restrict__ X,
    const float* __restrict__ Wenc,
    const float* __restrict__ benc,
    int*   __restrict__ candIdx,
    float* __restrict__ candVal)
{
  __shared__ unsigned int hist8[8][257];   // padded stride
  __shared__ unsigned int hist2[257];
  __shared__ int   inIdx[64];
  __shared__ float inVal[64];
  __shared__ int    bandIdx[BCAP];
  __shared__ double bandVal[BCAP];
  __shared__ int s_inCnt, s_bandCnt, s_sel, s_above, s_sel2;

  const int r = blockIdx.x;
  const int tid = threadIdx.x;
  const int wv = tid >> 6, lane = tid & 63;
  const int lc = lane & 7;
  const unsigned short* Prow = P + (size_t)r*DH;

#pragma unroll
  for (int k=0;k<8;k++) hist8[k][tid] = 0;
  hist2[tid] = 0;
  if (tid==0){ s_inCnt=0; s_bandCnt=0; }

  // row -> 8 named registers (32 VGPR)
  const usx8* Pv = (const usx8*)Prow;
  usx8 c0 = Pv[tid];        usx8 c1 = Pv[tid+256];
  usx8 c2 = Pv[tid+512];    usx8 c3 = Pv[tid+768];
  usx8 c4 = Pv[tid+1024];   usx8 c5 = Pv[tid+1280];
  usx8 c6 = Pv[tid+1536];   usx8 c7 = Pv[tid+1792];
  __syncthreads();

#define OMAP(b) (unsigned short)(((b) & 0x8000) ? (unsigned short)~(b) : (unsigned short)((b)|0x8000))
#define H1(CC) { _Pragma("unroll") for (int e=0;e<8;e++){ \
    unsigned short o = OMAP(CC[e]); atomicAdd(&hist8[lc][o>>8], 1u); } }
  H1(c0) H1(c1) H1(c2) H1(c3) H1(c4) H1(c5) H1(c6) H1(c7)
#undef H1
  __syncthreads();
  {
    unsigned int hs = 0;
#pragma unroll
    for (int c=0;c<8;c++) hs += hist8[c][tid];
    hist8[0][tid] = hs;
  }
  __syncthreads();

  if (tid < 64) {
    const int h0 = 255 - 4*tid;
    unsigned int c0_=hist8[0][h0], c1_=hist8[0][h0-1], c2_=hist8[0][h0-2], c3_=hist8[0][h0-3];
    unsigned int s = c0_+c1_+c2_+c3_;
    unsigned int Pi = s;
#pragma unroll
    for (int off=1; off<64; off<<=1){
      unsigned int t = __shfl_up(Pi, off);
      if (tid >= off) Pi += t;
    }
    unsigned long long mk = __ballot(Pi >= KSEL);
    int cr = (int)__builtin_ctzll(mk);
    if (tid == cr){
      unsigned int cum = Pi - s;
      unsigned int cc[4] = {c0_,c1_,c2_,c3_};
#pragma unroll
      for (int j=0;j<4;j++){
        if (cum + cc[j] >= KSEL){ s_sel = h0-j; s_above = (int)cum; break; }
        cum += cc[j];
      }
    }
  }
  __syncthreads();
  const int bsel = s_sel; const int cntAbove = s_above;

#define H2(CC) { _Pragma("unroll") for (int e=0;e<8;e++){ \
    unsigned short o = OMAP(CC[e]); \
    if ((int)(o>>8) == bsel) atomicAdd(&hist2[o & 0xff], 1u); } }
  H2(c0) H2(c1) H2(c2) H2(c3) H2(c4) H2(c5) H2(c6) H2(c7)
#undef H2
  __syncthreads();
  {
    const int K2 = KSEL - cntAbove;
    if (tid < 64) {
      const int h0 = 255 - 4*tid;
      unsigned int c0_=hist2[h0], c1_=hist2[h0-1], c2_=hist2[h0-2], c3_=hist2[h0-3];
      unsigned int s = c0_+c1_+c2_+c3_;
      unsigned int Pi = s;
#pragma unroll
      for (int off=1; off<64; off<<=1){
        unsigned int t = __shfl_up(Pi, off);
        if (tid >= off) Pi += t;
      }
      unsigned long long mk = __ballot(Pi >= (unsigned)K2);
      int cr = (int)__builtin_ctzll(mk);
      if (tid == cr){
        unsigned int cum = Pi - s;
        unsigned int cc[4] = {c0_,c1_,c2_,c3_};
#pragma unroll
        for (int j=0;j<4;j++){
          if (cum + cc[j] >= (unsigned)K2){ s_sel2 = h0-j; break; }
          cum += cc[j];
        }
      }
    }
  }
  __syncthreads();

  unsigned short To = (unsigned short)((bsel<<8) | s_sel2);
  unsigned short tb = (To & 0x8000) ? (unsigned short)(To ^ 0x8000) : (unsigned short)~To;
  const float T = h_bits2f(tb);
  const float hiv = T + 2.0f*EPS_SEL, lov = T - 2.0f*EPS_SEL;

#define EXT(CC, KK) { _Pragma("unroll") for (int e=0;e<8;e++){ \
    float v = h_bits2f(CC[e]); \
    if (v > hiv){ \
      int p = atomicAdd(&s_inCnt,1); \
      if (p < 64){ inIdx[p] = (tid + (KK)*256)*8 + e; inVal[p] = v; } \
    } else if (v >= lov){ \
      int p = atomicAdd(&s_bandCnt,1); \
      if (p < BCAP) bandIdx[p] = (tid + (KK)*256)*8 + e; \
    } } }
  EXT(c0,0) EXT(c1,1) EXT(c2,2) EXT(c3,3) EXT(c4,4) EXT(c5,5) EXT(c6,6) EXT(c7,7)
#undef EXT
#undef OMAP
  __syncthreads();
  const int m = s_inCnt < 64 ? s_inCnt : 64;
  const int B = s_bandCnt < BCAP ? s_bandCnt : BCAP;

  // exact f64 recompute for ambiguous band (4-way ILP partial sums)
  const float* Xr = X + (size_t)r*DI;
  for (int b=wv; b<B; b+=4){
    const int j = bandIdx[b];
    const float* Wr = Wenc + (size_t)j*DI;
    double s0=0.0, s1=0.0, s2=0.0, s3=0.0;
    for (int k0=lane; k0<DI; k0+=256){
      s0 = fma((double)Xr[k0],     (double)Wr[k0],     s0);
      s1 = fma((double)Xr[k0+64],  (double)Wr[k0+64],  s1);
      s2 = fma((double)Xr[k0+128], (double)Wr[k0+128], s2);
      s3 = fma((double)Xr[k0+192], (double)Wr[k0+192], s3);
    }
    double s = (s0+s1)+(s2+s3);
#pragma unroll
    for (int off=32; off>=1; off>>=1) s += __shfl_down(s, off);
    if (lane==0) bandVal[b] = s + (double)benc[j];
  }
  __syncthreads();

  int* ci = candIdx + (size_t)r*KSEL;
  float* cv = candVal + (size_t)r*KSEL;
  for (int t=tid; t<m; t+=256){ ci[t]=inIdx[t]; cv[t]=inVal[t]; }

  const int need = KSEL - m;
  if (tid < 64 && need > 0){
    unsigned int used = 0;
    for (int t=0;t<need;t++){
      double best = -1.0e300; int bi = -1;
#pragma unroll
      for (int sIt=0;sIt<4;sIt++){
        int b = tid + sIt*64;
        if (b < B && !((used>>sIt)&1)){
          double v = bandVal[b];
          if (v > best){ best=v; bi=b; }
        }
      }
#pragma unroll
      for (int off=32; off>=1; off>>=1){
        double ov = __shfl_down(best, off);
        int    oi = __shfl_down(bi,   off);
        if (ov > best){ best = ov; bi = oi; }
      }
      bi   = __shfl(bi, 0);
      best = __shfl(best, 0);
      if ((bi & 63) == tid) used |= 1u << (bi >> 6);
      if (tid == 0){
        ci[m+t] = bandIdx[bi];
        cv[m+t] = (float)best;
      }
    }
  }
}

// ---------------- sparse decode (fp8 gather) + loss partial ----------------
// R12: WdT stored fp8 e4m3 (x64 pre-scale); gather volume halves (2.1->1.05GB
// of L2/L3 traffic). sVal carries the 1/64 descale.
__global__ __launch_bounds__(256) void k_decode(
    float* __restrict__ outhat,
    const unsigned char* __restrict__ WdT8,
    const int*   __restrict__ candIdx,
    const float* __restrict__ candVal,
    const float* __restrict__ target,
    float* __restrict__ lossPartial)
{
  __shared__ int   sIdx[KSEL];
  __shared__ float sVal[KSEL];
  __shared__ float wsum[4];
  const int r = blockIdx.x, tid = threadIdx.x;
  if (tid < KSEL){
    sIdx[tid]=candIdx[(size_t)r*KSEL+tid];
    float v=candVal[(size_t)r*KSEL+tid];
    sVal[tid] = (v>0.f ? v : 0.f) * 0.015625f;   // /64 descale
  }
  __syncthreads();
  float* orow = outhat + (size_t)r*DO;
  float a[8];
  {
    float4 v0 = *(const float4*)(orow + tid*8);
    float4 v1 = *(const float4*)(orow + tid*8 + 4);
    a[0]=v0.x;a[1]=v0.y;a[2]=v0.z;a[3]=v0.w;a[4]=v1.x;a[5]=v1.y;a[6]=v1.z;a[7]=v1.w;
  }
#pragma unroll 4
  for (int c=0;c<KSEL;c++){
    const float v = sVal[c];
    const uint2 w = *(const uint2*)(WdT8 + (size_t)sIdx[c]*DO + tid*8);
    a[0] = fmaf(v, __builtin_amdgcn_cvt_f32_fp8(w.x, 0), a[0]);
    a[1] = fmaf(v, __builtin_amdgcn_cvt_f32_fp8(w.x, 1), a[1]);
    a[2] = fmaf(v, __builtin_amdgcn_cvt_f32_fp8(w.x, 2), a[2]);
    a[3] = fmaf(v, __builtin_amdgcn_cvt_f32_fp8(w.x, 3), a[3]);
    a[4] = fmaf(v, __builtin_amdgcn_cvt_f32_fp8(w.y, 0), a[4]);
    a[5] = fmaf(v, __builtin_amdgcn_cvt_f32_fp8(w.y, 1), a[5]);
    a[6] = fmaf(v, __builtin_amdgcn_cvt_f32_fp8(w.y, 2), a[6]);
    a[7] = fmaf(v, __builtin_amdgcn_cvt_f32_fp8(w.y, 3), a[7]);
  }
  const float* trow = target + (size_t)r*DO;
  float4 t0 = *(const float4*)(trow + tid*8);
  float4 t1 = *(const float4*)(trow + tid*8 + 4);
  float tt[8] = {t0.x,t0.y,t0.z,t0.w,t1.x,t1.y,t1.z,t1.w};
  float ls = 0.f;
#pragma unroll
  for (int j=0;j<8;j++){ float d = a[j]-tt[j]; ls = fmaf(d,d,ls); }
  {
    float4 v0 = {a[0],a[1],a[2],a[3]}, v1 = {a[4],a[5],a[6],a[7]};
    *(float4*)(orow + tid*8) = v0;
    *(float4*)(orow + tid*8 + 4) = v1;
  }
#pragma unroll
  for (int off=32; off>=1; off>>=1) ls += __shfl_down(ls, off);
  if ((tid&63)==0) wsum[tid>>6]=ls;
  __syncthreads();
  if (tid==0)
    lossPartial[r] = (wsum[0]+wsum[1]+wsum[2]+wsum[3]) * (1.0f/((float)NT*(float)DO));
}

__global__ __launch_bounds__(256) void k_lossreduce(const float* __restrict__ lp,
                                                    float* __restrict__ out)
{
  __shared__ double ws[4];
  double s=0.0;
  for (int i=threadIdx.x;i<NT;i+=256) s += (double)lp[i];
#pragma unroll
  for (int off=32; off>=1; off>>=1) s += __shfl_down(s, off);
  if ((threadIdx.x&63)==0) ws[threadIdx.x>>6]=s;
  __syncthreads();
  if (threadIdx.x==0) *out = (float)(ws[0]+ws[1]+ws[2]+ws[3]);
}

// ---------------- finalize h: zero + scatter ----------------
__global__ __launch_bounds__(256) void k_scatter(
    float* __restrict__ H, const int* __restrict__ candIdx, const float* __restrict__ candVal)
{
  const int r=blockIdx.x, tid=threadIdx.x;
  float* hr = H + (size_t)r*DH;
  const float4 z = {0.f,0.f,0.f,0.f};
#pragma unroll
  for (int i=0;i<16;i++) ((float4*)hr)[tid + i*256] = z;
  __syncthreads();
  if (tid<KSEL){
    float v = candVal[(size_t)r*KSEL+tid];
    hr[candIdx[(size_t)r*KSEL+tid]] = v>0.f ? v : 0.f;
  }
}

extern "C" void kernel_launch(void* const* d_in, const int* in_sizes, int n_in,
                              void* d_out, int out_size, void* d_ws, size_t ws_size,
                              hipStream_t stream)
{
  const float* X     = (const float*)d_in[0];
  const float* tgt   = (const float*)d_in[1];
  const float* Wenc  = (const float*)d_in[2];
  const float* benc  = (const float*)d_in[3];
  const float* Wdec  = (const float*)d_in[4];
  const float* bdec  = (const float*)d_in[5];
  const float* Wskip = (const float*)d_in[6];
  const float* bskip = (const float*)d_in[7];

  float* out     = (float*)d_out;
  float* outhat  = out;
  float* H       = out + (size_t)NT*DO;
  float* lossOut = out + (size_t)NT*DO + (size_t)NT*DH;

  // h-region scratch plan (dead until k_scatter)
  char* hb = (char*)H;
  unsigned short* P      = (unsigned short*)hb;
  char* U                = hb + (size_t)NT*DH*2;
  unsigned short* Xh     = (unsigned short*)U;
  unsigned short* Wench  = (unsigned short*)(U + (size_t)NT*DI*2);
  unsigned short* Wskiph = (unsigned short*)(U + (size_t)NT*DI*2 + (size_t)DH*DI*2);
  unsigned char*  WdT8   = (unsigned char*)(U + (size_t)NT*DI*2 + (size_t)DH*DI*2 + (size_t)DO*DI*2);

  int*   candIdx    = (int*)d_ws;
  float* candVal    = (float*)((char*)d_ws + (size_t)NT*KSEL*4);
  float* lossPartial= (float*)((char*)d_ws + (size_t)NT*KSEL*8);

  k_cvt<<<NT*DI/8/256, 256, 0, stream>>>(X, Xh, NT*DI/8);
  k_cvt<<<DH*DI/8/256, 256, 0, stream>>>(Wenc, Wench, DH*DI/8);
  k_cvt<<<DO*DI/8/256, 256, 0, stream>>>(Wskip, Wskiph, DO*DI/8);
  k_transpose_cvt8<<<dim3(DO/64, DH/64), 256, 0, stream>>>(Wdec, WdT8);

  k_gemm_enc8<<<dim3(NT/256, DH/256), 512, 0, stream>>>(Xh, Wench, benc, P);
  k_topk<<<NT, 256, 0, stream>>>(P, X, Wenc, benc, candIdx, candVal);
  k_gemm_skip<<<dim3(NT/128, DO/128), 256, 0, stream>>>(Xh, Wskiph, bdec, bskip, (void*)outhat);
  k_decode<<<NT, 256, 0, stream>>>(outhat, WdT8, candIdx, candVal, tgt, lossPartial);
  k_lossreduce<<<1, 256, 0, stream>>>(lossPartial, lossOut);
  k_scatter<<<NT, 256, 0, stream>>>(H, candIdx, candVal);
}